// Round 6
// baseline (379.823 us; speedup 1.0000x reference)
//
#include <hip/hip_runtime.h>
#include <hip/hip_bf16.h>
#include <hip/hip_cooperative_groups.h>

namespace cg = cooperative_groups;

// Problem constants (reference: B=2, N=20000, K=16, DIM=256)
// Established facts (R1-R16):
//   - float tensors fp32; idx int32/int64 runtime-detected; d_out fp32
//   - MFMA 16x16x32_bf16 gemm-BT fragments + C/D map verified
//   - R5-R8: global->VGPR weight loads serialize; use LDS (DMA) for weights.
//   - R11: final weight-stationary (250 blks x 512 thr, 128 KB LDS, ONE
//     barrier, 5x64-row tiles) = 39.4 us. KNOWN GOOD; P4 below is this body.
//   - R12-R14: every dispatch is latency/ramp-bound (geom pinned ~40 us
//     across 3 implementations with 10x work delta). Co-dispatch helped
//     (-10.6). Useful work ~110 us vs 196 wall -> ~90 us = serialization.
//   - R15 REGRESSION (reverted): gather2 fused into final doubled gather
//     work per col-half pair + thrashed 4MB per-XCD L2 (212 MB FETCH) +
//     8-way LDS write conflicts on 136-short stride.
//   - R16 (this round): ONE cooperative mega-kernel, 250 blocks x 512 thr
//     (128 KB LDS -> 1 blk/CU, co-resident), grid.sync() between phases:
//     P0 prep -> P1 geom+mlp (Wnt DMA under geom) -> P2 gather1 ->
//     P3 final-weight DMA + gather2 (DMA lands under gather) -> P4 final.
//     Deletes 4 dispatch boundaries + final's weight-wait.
//   - LDS quarter-wave phasing: addr = f(lane&15)*16 + (lane>>4)*const
//     (const = multiple of 1 KB) is conflict-free (R9/R11 measured 0).
#define BN   40000
#define NPTS 20000
#define KNN  16
#define DIM  256

typedef __attribute__((ext_vector_type(8))) short bf16x8;   // 8 bf16 = 4 VGPRs
typedef __attribute__((ext_vector_type(4))) float f32x4;
typedef __attribute__((ext_vector_type(16))) float f32x16;

__device__ __forceinline__ float lrelu(float v) { return fmaxf(v, 0.1f * v); }
__device__ __forceinline__ float bs2f(short s) {
    union { unsigned u; float f; } c; c.u = ((unsigned)(unsigned short)s) << 16;
    return c.f;
}
__device__ __forceinline__ short f2bs(float f) {
    __hip_bfloat16 h = __float2bfloat16(f);           // RNE
    return *reinterpret_cast<short*>(&h);
}
__device__ __forceinline__ bf16x8 ldf32_bf16x8(const float* p) {
    const float4 a = ((const float4*)p)[0];
    const float4 b = ((const float4*)p)[1];
    bf16x8 r;
    r[0]=f2bs(a.x); r[1]=f2bs(a.y); r[2]=f2bs(a.z); r[3]=f2bs(a.w);
    r[4]=f2bs(b.x); r[5]=f2bs(b.y); r[6]=f2bs(b.z); r[7]=f2bs(b.w);
    return r;
}

// async global->LDS, 16 B per lane; lds dst = wave-uniform base + lane*16.
__device__ __forceinline__ void dma16(const void* g, void* l) {
    __builtin_amdgcn_global_load_lds(
        (const __attribute__((address_space(1))) unsigned int*)g,
        (__attribute__((address_space(3))) unsigned int*)l, 16, 0, 0);
}

// ---------------------------------------------------------------------------
// Persistent cooperative mega-kernel. 250 blocks x 512 threads, 128 KB LDS.
// ---------------------------------------------------------------------------
__global__ void __launch_bounds__(512, 1) mega_kernel(
    const float* __restrict__ geom,      // [BN,16,4]
    const float* __restrict__ W1, const float* __restrict__ B1,   // [64,4],[64]
    const float* __restrict__ W2, const float* __restrict__ B2,   // [128,4],[128]
    const float* __restrict__ X,         // [BN,256] input (also RES)
    const int* __restrict__ idxw,
    const float* __restrict__ Wf, const float* __restrict__ Wi,   // [256,256]
    const float* __restrict__ Wn,                                  // [64,256]
    const float* __restrict__ b_init,    // [64]
    const float* __restrict__ Bf, const float* __restrict__ Bi,   // [256]
    short* __restrict__ Wt, short* __restrict__ Wnt,
    int* __restrict__ flagp,
    __hip_bfloat16* __restrict__ x1,     // [BN,64]  (d_out scratch)
    __hip_bfloat16* __restrict__ x2,     // [BN,128]
    __hip_bfloat16* __restrict__ x3,     // [BN,256]
    float* __restrict__ OUT)             // [BN,256] fp32
{
    __shared__ short lw[65536];          // 128 KB: P1 Wnt (32 KB) / P4 weights
    __shared__ int dred[8];
    cg::grid_group grid = cg::this_grid();
    const int tid  = threadIdx.x;
    const int wave = tid >> 6, lane = tid & 63;
    const int bid  = blockIdx.x;

    // ================= P0: weight convert + idx-dtype detect =================
    if (bid < 72) {                      // 72*512 = 36864 exactly
        int t = bid * 512 + tid;
        if (t < 32768) {                 // Wf (t<16384) / Wi -> tiled Wt
            int mat = (t >> 14) & 1;
            int tt  = t & 16383;
            float4 v = mat ? ((const float4*)Wi)[tt] : ((const float4*)Wf)[tt];
            int n  = tt >> 6;
            int k  = (tt & 63) * 4;
            int kk = k >> 5, q = (k >> 3) & 3, j = k & 7;
            short4 o; o.x=f2bs(v.x); o.y=f2bs(v.y); o.z=f2bs(v.z); o.w=f2bs(v.w);
            *(short4*)(Wt + ((size_t)((kk*2 + mat)*4 + q))*2048 + n*8 + j) = o;
        } else {                          // W_init -> tiled Wnt (n<64)
            int tt = t - 32768;           // < 4096
            float4 v = ((const float4*)Wn)[tt];
            int n  = tt >> 6;
            int k  = (tt & 63) * 4;
            int kk = k >> 5, q = (k >> 3) & 3, j = k & 7;
            short4 o; o.x=f2bs(v.x); o.y=f2bs(v.y); o.z=f2bs(v.z); o.w=f2bs(v.w);
            *(short4*)(Wnt + ((size_t)((kk*4 + q)*64 + n))*8 + j) = o;
        }
    } else if (bid == 72) {              // detect: odd words of first 128 KB
        int v = 0;
#pragma unroll
        for (int it = 0; it < 32; ++it)
            v |= idxw[2 * (tid + it * 512) + 1];
#pragma unroll
        for (int s = 1; s < 64; s <<= 1) v |= __shfl_xor(v, s, 64);
        if (lane == 0) dred[wave] = v;
        __syncthreads();
        if (tid == 0) {
            int r0 = 0;
#pragma unroll
            for (int i = 0; i < 8; ++i) r0 |= dred[i];
            *flagp = (r0 != 0) ? 1 : 0;
        }
    }
    grid.sync();
    const int dual = (*(volatile const int*)flagp == 0) ? 2 : 1;

    // ================= P1: geom MLP (all waves) + mlp_init ==================
    {
        // Wnt -> LDS (32 KB) async; lands under geom compute.
        {
            const char* W8 = (const char*)Wnt;
            char* L8 = (char*)lw;
#pragma unroll
            for (int rd = 0; rd < 4; ++rd) {
                int off = (wave * 4 + rd) * 1024 + lane * 16;
                dma16(W8 + off, L8 + off);
            }
        }
        // ---- geom: wave wglob handles 10 point-pairs (2000 x 10 = 20000) ----
        const int c31 = lane & 31;
        const int hi  = lane >> 5;
        const int wglob = bid * 8 + wave;            // 0..1999
        bf16x8 bfr[6]; float bv[6];
#pragma unroll
        for (int tt = 0; tt < 6; ++tt) {
            bfr[tt] = (bf16x8){0,0,0,0,0,0,0,0};
            const float* Wrow;
            if (tt < 2) { Wrow = W1 + (size_t)(tt*32 + c31) * 4;     bv[tt] = B1[tt*32 + c31]; }
            else        { Wrow = W2 + (size_t)((tt-2)*32 + c31) * 4; bv[tt] = B2[(tt-2)*32 + c31]; }
            if (hi == 0) {
                const float4 w4 = *(const float4*)Wrow;
                bfr[tt][0]=f2bs(w4.x); bfr[tt][1]=f2bs(w4.y);
                bfr[tt][2]=f2bs(w4.z); bfr[tt][3]=f2bs(w4.w);
            }
        }
        f32x16 ZR;
#pragma unroll
        for (int i = 0; i < 16; ++i) ZR[i] = 0.f;

        float4 g = (float4){0.f,0.f,0.f,0.f};
        if (hi == 0)
            g = *(const float4*)(geom +
                ((size_t)((wglob * 10) * 2 + (c31 >> 4)) * KNN + (c31 & 15)) * 4);
#pragma unroll 1
        for (int it = 0; it < 10; ++it) {
            const int pg = (wglob * 10 + it) * 2;
            const float4 gc = g;
            if (it < 9 && hi == 0)                        // prefetch next pair
                g = *(const float4*)(geom +
                    ((size_t)(pg + 2 + (c31 >> 4)) * KNN + (c31 & 15)) * 4);
            bf16x8 a = (bf16x8){0,0,0,0,0,0,0,0};
            if (hi == 0) { a[0]=f2bs(gc.x); a[1]=f2bs(gc.y); a[2]=f2bs(gc.z); a[3]=f2bs(gc.w); }
            f32x16 acc[6];
#pragma unroll
            for (int tt = 0; tt < 6; ++tt)
                acc[tt] = __builtin_amdgcn_mfma_f32_32x32x16_bf16(a, bfr[tt], ZR, 0, 0, 0);
#pragma unroll
            for (int tt = 0; tt < 6; ++tt) {
                float sA = 0.f, sB = 0.f;
#pragma unroll
                for (int i = 0; i < 8; ++i)  sA += lrelu(acc[tt][i]     + bv[tt]);
#pragma unroll
                for (int i = 0; i < 8; ++i)  sB += lrelu(acc[tt][i + 8] + bv[tt]);
                sA += __shfl_xor(sA, 32, 64);
                sB += __shfl_xor(sB, 32, 64);
                const float s = (hi ? sB : sA) * (1.f / 16.f);
                const short v = f2bs(s);
                if (tt < 2) ((short*)x2)[(size_t)(pg + hi) * 128 + tt*32 + c31] = v;
                else        ((short*)x3)[(size_t)(pg + hi) * 256 + (tt-2)*32 + c31] = v;
            }
        }
        __syncthreads();                 // Wnt landed (vmcnt drain) + geom done

        // ---- mlp_init: block rows [bid*160, bid*160+160), 10 tiles x 16 ----
        const int r = lane & 15, q = lane >> 4;
#pragma unroll 1
        for (int ti = wave; ti < 10; ti += 8) {
            const int m0 = bid * 160 + ti * 16;
            const float* Xs = X + (size_t)(m0 + r) * DIM + q * 8;
            bf16x8 a[8];
#pragma unroll
            for (int kk = 0; kk < 8; ++kk) a[kk] = ldf32_bf16x8(Xs + kk * 32);
            f32x4 acc[4];
#pragma unroll
            for (int nt = 0; nt < 4; ++nt) acc[nt] = (f32x4){0.f,0.f,0.f,0.f};
#pragma unroll
            for (int kk = 0; kk < 8; ++kk) {
#pragma unroll
                for (int nt = 0; nt < 4; ++nt) {
                    bf16x8 b = *(const bf16x8*)&lw[((kk*4 + q)*64 + nt*16 + r) * 8];
                    acc[nt] = __builtin_amdgcn_mfma_f32_16x16x32_bf16(a[kk], b, acc[nt], 0, 0, 0);
                }
            }
#pragma unroll
            for (int nt = 0; nt < 4; ++nt) {
                int col = nt * 16 + r;
                float bvx = b_init[col];
#pragma unroll
                for (int i = 0; i < 4; ++i) {
                    float v = lrelu(acc[nt][i] + bvx);
                    x1[(size_t)(m0 + q*4 + i) * 64 + col] = __float2bfloat16(v);
                }
            }
        }
    }
    grid.sync();

    // ================= P2: gather1 (x1 -> x2[:,64:128]) =====================
#pragma unroll 1
    for (int it = 0; it < 3; ++it) {
        int t = bid * 512 + tid + it * 128000;      // 3 x 128000 covers 320000
        if (t < 320000) {
            int p = t >> 3, j = t & 7;
            int base = (p >= NPTS) ? NPTS : 0;
            int i0 = idxw[((size_t)p * 16 + 2*j)     * dual];
            int i1 = idxw[((size_t)p * 16 + 2*j + 1) * dual];
            int g8 = lane & 56;
            float acc[8];
#pragma unroll
            for (int i = 0; i < 8; ++i) acc[i] = 0.f;
#pragma unroll
            for (int k = 0; k < 8; ++k) {
                int rA = base + __shfl(i0, g8 + k, 64);
                int rB = base + __shfl(i1, g8 + k, 64);
                bf16x8 vA = *(const bf16x8*)((const short*)x1 + (size_t)rA * 64 + j * 8);
                bf16x8 vB = *(const bf16x8*)((const short*)x1 + (size_t)rB * 64 + j * 8);
#pragma unroll
                for (int i = 0; i < 8; ++i) acc[i] += bs2f(vA[i]) + bs2f(vB[i]);
            }
            bf16x8 o;
#pragma unroll
            for (int i = 0; i < 8; ++i) o[i] = f2bs(acc[i] * (1.f/16.f));
            *(bf16x8*)((short*)x2 + (size_t)p * 128 + 64 + j * 8) = o;
        }
    }
    grid.sync();

    // ===== P3: final-weight DMA (lands under gather2) + gather2 =============
    {
        const char* WtB = (const char*)Wt;
        char* L = (char*)lw;
        const int ch = bid & 1;
#pragma unroll
        for (int i = 0; i < 16; ++i) {
            int c = wave * 8 + (i >> 1);           // 0..63: (mat*8+kk)*4+qq
            int d = i & 1;                          // half-chunk (1 KB)
            int mat = c >> 5, kk = (c >> 2) & 7, qq = c & 3;
            int src_sh = ((kk * 2 + mat) * 4 + qq) * 2048 + ch * 1024;
            dma16(WtB + (size_t)src_sh * 2 + d * 1024 + lane * 16,
                  L + (c * 2 + d) * 1024 + lane * 16);
        }
    }
#pragma unroll 1
    for (int it = 0; it < 5; ++it) {
        int t = bid * 512 + tid + it * 128000;      // 5 x 128000 = 640000 exact
        int p = t >> 4, j = t & 15;
        int base = (p >= NPTS) ? NPTS : 0;
        int myi = idxw[((size_t)p * 16 + j) * dual];
        int g16 = lane & 48;
        float acc[8];
#pragma unroll
        for (int i = 0; i < 8; ++i) acc[i] = 0.f;
#pragma unroll
        for (int k = 0; k < KNN; ++k) {
            int row = base + __shfl(myi, g16 + k, 64);
            bf16x8 v = *(const bf16x8*)((const short*)x2 + (size_t)row * 128 + j * 8);
#pragma unroll
            for (int i = 0; i < 8; ++i) acc[i] += bs2f(v[i]);
        }
        bf16x8 o;
#pragma unroll
        for (int i = 0; i < 8; ++i) o[i] = f2bs(acc[i] * (1.f/16.f));
        *(bf16x8*)((short*)x3 + (size_t)p * 256 + 128 + j * 8) = o;
    }
    __syncthreads();                     // drain weight-DMA vmcnt in-block
    grid.sync();

    // ================= P4: final (R11 body, weights resident) ===============
    {
        const int r = lane & 15, q = lane >> 4;
        const int rg = wave >> 1, cgp = wave & 1;   // 4 row-grp x 2 col-grp
        const int ch = bid & 1;
        const int p0 = (bid >> 1) * 320;            // 125 x 320 = 40000
        const int cb = ch * 128 + cgp * 64;
        float bfv[4], biv[4];
#pragma unroll
        for (int nt = 0; nt < 4; ++nt) {
            bfv[nt] = Bf[cb + nt * 16 + r];
            biv[nt] = Bi[cb + nt * 16 + r];
        }
        const short* bpf = lw + q * 1024 + (cgp * 64 + r) * 8;   // mat f (Wf)
        const short* bpi = bpf + 32768;                           // mat i (Wi)

#pragma unroll 1
        for (int tt = 0; tt < 5; ++tt) {
            const int row = p0 + tt * 64 + rg * 16 + r;
            const short* x3r = (const short*)x3 + (size_t)row * DIM + q * 8;
            const float* rsr = X + (size_t)row * DIM + q * 8;

            bf16x8 a1[8];
            float4 rw[16];
#pragma unroll
            for (int kk = 0; kk < 8; ++kk) {
                rw[2*kk]   = ((const float4*)rsr)[kk * 8];
                rw[2*kk+1] = ((const float4*)rsr)[kk * 8 + 1];
                a1[kk] = *(const bf16x8*)(x3r + kk * 32);
            }
            f32x4 acc1[4], acc2[4];
#pragma unroll
            for (int nt = 0; nt < 4; ++nt) {
                acc1[nt] = (f32x4){0.f,0.f,0.f,0.f};
                acc2[nt] = (f32x4){0.f,0.f,0.f,0.f};
            }
#pragma unroll
            for (int kk = 0; kk < 8; ++kk) {
                bf16x8 a2;
                {
                    const float4 lo = rw[2*kk], hi2 = rw[2*kk+1];
                    a2[0]=f2bs(lo.x);  a2[1]=f2bs(lo.y);  a2[2]=f2bs(lo.z);  a2[3]=f2bs(lo.w);
                    a2[4]=f2bs(hi2.x); a2[5]=f2bs(hi2.y); a2[6]=f2bs(hi2.z); a2[7]=f2bs(hi2.w);
                }
#pragma unroll
                for (int nt = 0; nt < 4; ++nt) {
                    bf16x8 b1 = *(const bf16x8*)(bpf + kk * 4096 + nt * 128);
                    bf16x8 b2 = *(const bf16x8*)(bpi + kk * 4096 + nt * 128);
                    acc1[nt] = __builtin_amdgcn_mfma_f32_16x16x32_bf16(a1[kk], b1, acc1[nt], 0, 0, 0);
                    acc2[nt] = __builtin_amdgcn_mfma_f32_16x16x32_bf16(a2,    b2, acc2[nt], 0, 0, 0);
                }
            }
#pragma unroll
            for (int nt = 0; nt < 4; ++nt) {
                const int col = cb + nt * 16 + r;
#pragma unroll
                for (int i = 0; i < 4; ++i) {
                    float v = lrelu(acc1[nt][i] + bfv[nt]) + lrelu(acc2[nt][i] + biv[nt]);
                    OUT[(size_t)(p0 + tt * 64 + rg * 16 + q * 4 + i) * DIM + col] = v;
                }
            }
        }
    }
}

// ---------------------------------------------------------------------------
extern "C" void kernel_launch(void* const* d_in, const int* in_sizes, int n_in,
                              void* d_out, int out_size, void* d_ws, size_t ws_size,
                              hipStream_t stream)
{
    const float* input  = (const float*)d_in[0];   // [2,20000,256]
    const float* geom   = (const float*)d_in[1];   // [2,20000,16,4]
    const int*   idxw   = (const int*)d_in[2];     // int32/int64 (detected)
    const float* W_init = (const float*)d_in[3];   // [64,256]
    const float* b_init = (const float*)d_in[4];
    const float* W_l1   = (const float*)d_in[5];   // [64,4]
    const float* b_l1   = (const float*)d_in[6];
    const float* W_l2   = (const float*)d_in[7];   // [128,4]
    const float* b_l2   = (const float*)d_in[8];
    const float* W_fin  = (const float*)d_in[9];   // [256,256]
    const float* b_fin  = (const float*)d_in[10];
    const float* W_id   = (const float*)d_in[11];  // [256,256]
    const float* b_id   = (const float*)d_in[12];
    float* out = (float*)d_out;                    // [2,20000,256] fp32

    // ws layout (<= 35.84 MB, proven safe R4-R15):
    //   flag @0 (16B)
    //   Wt  tiled bf16 256KB @16 ; Wnt tiled bf16 32KB @16+262144
    //   x2  [BN,128] bf16 @16+5.12e6
    //   x3  [BN,256] bf16 @16+15.36e6
    // x1 [BN,64] bf16 lives in d_out scratch; consumed in P2, then P4
    // overwrites all of d_out.
    char* ws = (char*)d_ws;
    int* flag = (int*)ws;
    short* Wt  = (short*)(ws + 16);
    short* Wnt = (short*)(ws + 16 + 262144);
    __hip_bfloat16* x2 = (__hip_bfloat16*)(ws + 16 + 5120000);
    __hip_bfloat16* x3 = (__hip_bfloat16*)(ws + 16 + 15360000);
    __hip_bfloat16* x1 = (__hip_bfloat16*)d_out;   // scratch, dead after P2

    void* args[] = {
        (void*)&geom, (void*)&W_l1, (void*)&b_l1, (void*)&W_l2, (void*)&b_l2,
        (void*)&input, (void*)&idxw,
        (void*)&W_fin, (void*)&W_id, (void*)&W_init,
        (void*)&b_init, (void*)&b_fin, (void*)&b_id,
        (void*)&Wt, (void*)&Wnt, (void*)&flag,
        (void*)&x1, (void*)&x2, (void*)&x3, (void*)&out
    };
    hipLaunchCooperativeKernel((void*)mega_kernel, dim3(250), dim3(512),
                               args, 0, stream);
}

// Round 7
// 210.369 us; speedup vs baseline: 1.8055x; 1.8055x over previous
//
#include <hip/hip_runtime.h>
#include <hip/hip_bf16.h>

// Problem constants (reference: B=2, N=20000, K=16, DIM=256)
// Established facts (R1-R17):
//   - float tensors fp32; idx int32/int64 runtime-detected; d_out fp32
//   - MFMA 16x16x32_bf16 gemm-BT fragments + C/D map verified
//   - R5-R8: global->VGPR weight loads serialize; use LDS (DMA) for weights.
//   - R11: final weight-stationary col-half (250x512, 128 KB LDS) = 39.4 us.
//   - R12-R14: dispatches are latency/ramp-bound (geom pinned ~40 us across
//     3 impls with 10x work delta). Co-dispatch helped (-10.6) -> 195.8 BEST.
//   - R15 REGRESSION: gather2-in-final duplicated gather per col-half pair,
//     thrashed L2 (212 MB FETCH), 8-way LDS write conflicts. Reverted.
//   - R16 REGRESSION (mega cooperative kernel, 252 us): gathers are
//     LATENCY-BOUND, scale ~1/waves. 128 KB LDS forced 8 waves/CU (vs ~32
//     standalone) -> gather phases 3-4x slower. NEVER cap occupancy of the
//     gather phases. Reverted to R14 chain.
//   - R17 (this round): (a) final -> col-QUARTER weight-stationary:
//     500 blks x 256 thr x 64 KB LDS, 2 blk/CU (two overlapping DMA/compute
//     streams per CU, halved DMA drain, same 32 MB weight traffic; extra A
//     re-reads are L3-absorbed per R0-R4 FETCH data). (b) stage2-mlp A-loads:
//     raw float4 burst (8 outstanding) + deferred cvt, 2 groups of 4 kk
//     (VGPR < 128), replacing per-kk load->cvt serialization.
//   - LDS quarter-wave phasing: byte addr = r*16 + q*(multiple of 1 KB) +
//     const is conflict-free (R9/R11 measured 0; b128 processes 16
//     lanes/phase; within a quarter-wave 2 lanes/bank = free per m136).
#define BN   40000
#define NPTS 20000
#define KNN  16
#define DIM  256

typedef __attribute__((ext_vector_type(8))) short bf16x8;   // 8 bf16 = 4 VGPRs
typedef __attribute__((ext_vector_type(4))) float f32x4;
typedef __attribute__((ext_vector_type(16))) float f32x16;

__device__ __forceinline__ float lrelu(float v) { return fmaxf(v, 0.1f * v); }
__device__ __forceinline__ float bs2f(short s) {
    union { unsigned u; float f; } c; c.u = ((unsigned)(unsigned short)s) << 16;
    return c.f;
}
__device__ __forceinline__ short f2bs(float f) {
    __hip_bfloat16 h = __float2bfloat16(f);           // RNE
    return *reinterpret_cast<short*>(&h);
}
__device__ __forceinline__ bf16x8 ldf32_bf16x8(const float* p) {
    const float4 a = ((const float4*)p)[0];
    const float4 b = ((const float4*)p)[1];
    bf16x8 r;
    r[0]=f2bs(a.x); r[1]=f2bs(a.y); r[2]=f2bs(a.z); r[3]=f2bs(a.w);
    r[4]=f2bs(b.x); r[5]=f2bs(b.y); r[6]=f2bs(b.z); r[7]=f2bs(b.w);
    return r;
}

// async global->LDS, 16 B per lane; lds dst = wave-uniform base + lane*16.
__device__ __forceinline__ void dma16(const void* g, void* l) {
    __builtin_amdgcn_global_load_lds(
        (const __attribute__((address_space(1))) unsigned int*)g,
        (__attribute__((address_space(3))) unsigned int*)l, 16, 0, 0);
}

// ---------------------------------------------------------------------------
// prep: idx-dtype detect (block 0) + weight conversion (blocks 1..144).
// conv: Wf,Wi -> kk-tiled bf16 Wt[kk][mat][q][n][8] (32 KB per kk slice);
//       W_init -> kk-tiled Wnt[kk][q][n<64][8] (32 KB total).
// ---------------------------------------------------------------------------
__global__ void __launch_bounds__(256) prep_kernel(
    const int* __restrict__ idxw, int* __restrict__ flag,
    const float* __restrict__ Wf, const float* __restrict__ Wi,   // [256,256]
    const float* __restrict__ Wn,                                  // [64,256]
    short* __restrict__ Wt, short* __restrict__ Wnt)
{
    if (blockIdx.x == 0) {               // ---- detect block (no atomics) ----
        __shared__ int red[256];
        int t = threadIdx.x;
        int v = 0;
#pragma unroll
        for (int it = 0; it < 64; ++it)
            v |= idxw[2 * (t + it * 256) + 1];       // odd words, first 128 KB
        red[t] = v;
        __syncthreads();
        for (int s = 128; s > 0; s >>= 1) {
            if (t < s) red[t] |= red[t + s];
            __syncthreads();
        }
        if (t == 0) *flag = (red[0] != 0) ? 1 : 0;
        return;
    }
    int t = (blockIdx.x - 1) * 256 + threadIdx.x;   // < 36864 exactly
    if (t < 32768) {                 // Wf (t<16384) / Wi -> tiled Wt
        int mat = (t >> 14) & 1;
        int tt  = t & 16383;
        float4 v = mat ? ((const float4*)Wi)[tt] : ((const float4*)Wf)[tt];
        int n  = tt >> 6;
        int k  = (tt & 63) * 4;
        int kk = k >> 5, q = (k >> 3) & 3, j = k & 7;
        short4 o; o.x=f2bs(v.x); o.y=f2bs(v.y); o.z=f2bs(v.z); o.w=f2bs(v.w);
        *(short4*)(Wt + ((size_t)((kk*2 + mat)*4 + q))*2048 + n*8 + j) = o;
    } else {                          // W_init -> tiled Wnt (n<64)
        int tt = t - 32768;           // < 4096
        float4 v = ((const float4*)Wn)[tt];
        int n  = tt >> 6;
        int k  = (tt & 63) * 4;
        int kk = k >> 5, q = (k >> 3) & 3, j = k & 7;
        short4 o; o.x=f2bs(v.x); o.y=f2bs(v.y); o.z=f2bs(v.z); o.w=f2bs(v.w);
        *(short4*)(Wnt + ((size_t)((kk*4 + q)*64 + n))*8 + j) = o;
    }
}

// ---------------------------------------------------------------------------
// stage2: geom MLPs (blocks 0..624) CO-DISPATCHED with mlp_init (625..1249).
// No cross-dependence: geom reads geom+W1/W2, writes x2[:,0:64]/x3[:,0:128];
// mlp reads input+Wnt(prep)+b_init, writes x1. Disjoint outputs.
//
// geom (persistent waves): wave = blockIdx*4+wv handles 8 point-pairs.
//   Weights/biases hoisted ONCE per wave; next pair's geom float4 prefetched.
//   A = [32 x K16] (rows = 2x16 neighbors, cols 0..3 real), 6 B-tiles cover
//   192 channels. C: col=lane&31, row=(reg&3)+8*(reg>>2)+4*(lane>>5);
//   per-point mean = 8-reg in-lane lrelu-sum + shfl_xor(32).
//
// mlp_init: x1 = LR(input @ W_init^T + b_init). Weights (32 KB tiled) DMA'd
//   to LDS once, ONE barrier; A-loads R17: raw float4 bursts (8 outstanding)
//   + deferred cvt, 2 groups of 4 kk. Inner loop = pure ds_read + MFMA.
//   x1 lives in d_out scratch (consumed by gather1 before final overwrites).
// ---------------------------------------------------------------------------
__global__ void __launch_bounds__(256) stage2_kernel(
    const float* __restrict__ geom,      // [BN,16,4]
    const float* __restrict__ W1, const float* __restrict__ B1,   // [64,4],[64]
    const float* __restrict__ W2, const float* __restrict__ B2,   // [128,4],[128]
    const float* __restrict__ X,         // [BN,256] input
    const short* __restrict__ Wnt,       // [kk][q][64][8] bf16, 32 KB
    const float* __restrict__ b_init,    // [64]
    __hip_bfloat16* __restrict__ x2,     // [BN,128]
    __hip_bfloat16* __restrict__ x3,     // [BN,256]
    __hip_bfloat16* __restrict__ x1)     // [BN,64] bf16 (d_out scratch)
{
    __shared__ short wbuf[16384];        // 32 KB (used by mlp blocks only)

    if (blockIdx.x >= 625) {             // ---------------- mlp_init ----------
        int bid = blockIdx.x - 625;      // 0..624
        int t = threadIdx.x;
        int wave = t >> 6, lane = t & 63;
        int r = lane & 15, q = lane >> 4;
        // DMA the full 32 KB (4 waves x 8 x 1 KB, linear copy)
        {
            const char* W8 = (const char*)Wnt;
            char* L8 = (char*)wbuf;
#pragma unroll
            for (int rd = 0; rd < 8; ++rd) {
                int off = (wave * 8 + rd) * 1024 + lane * 16;
                dma16(W8 + off, L8 + off);
            }
        }
        int m0 = bid * 64 + wave * 16;
        const float4* X4 = (const float4*)(X + (size_t)(m0 + r) * DIM + q * 8);
        bf16x8 a[8];
        // R17: burst 8 raw float4 loads, then convert (2 groups of 4 kk)
#pragma unroll
        for (int g = 0; g < 2; ++g) {
            float4 rwm[8];
#pragma unroll
            for (int kk = 0; kk < 4; ++kk) {
                rwm[2*kk]   = X4[(g*4 + kk) * 8];
                rwm[2*kk+1] = X4[(g*4 + kk) * 8 + 1];
            }
#pragma unroll
            for (int kk = 0; kk < 4; ++kk) {
                const float4 lo = rwm[2*kk], hi2 = rwm[2*kk+1];
                bf16x8 av;
                av[0]=f2bs(lo.x);  av[1]=f2bs(lo.y);  av[2]=f2bs(lo.z);  av[3]=f2bs(lo.w);
                av[4]=f2bs(hi2.x); av[5]=f2bs(hi2.y); av[6]=f2bs(hi2.z); av[7]=f2bs(hi2.w);
                a[g*4 + kk] = av;
            }
        }
        __syncthreads();

        f32x4 acc[4];
#pragma unroll
        for (int nt = 0; nt < 4; ++nt) acc[nt] = (f32x4){0.f,0.f,0.f,0.f};
#pragma unroll
        for (int kk = 0; kk < 8; ++kk) {
#pragma unroll
            for (int nt = 0; nt < 4; ++nt) {
                bf16x8 b = *(const bf16x8*)&wbuf[((kk*4 + q)*64 + nt*16 + r) * 8];
                acc[nt] = __builtin_amdgcn_mfma_f32_16x16x32_bf16(a[kk], b, acc[nt], 0, 0, 0);
            }
        }
#pragma unroll
        for (int nt = 0; nt < 4; ++nt) {
            int col = nt * 16 + r;
            float bvx = b_init[col];
#pragma unroll
            for (int i = 0; i < 4; ++i) {
                float v = lrelu(acc[nt][i] + bvx);
                x1[(size_t)(m0 + q*4 + i) * 64 + col] = __float2bfloat16(v);
            }
        }
        return;
    }

    // ---------------- geom: 625 blocks x 4 waves x 8 pairs = 40000 pts -----
    const int lane = threadIdx.x & 63;
    const int wv   = threadIdx.x >> 6;
    const int c31  = lane & 31;
    const int hi   = lane >> 5;
    const int wglob = blockIdx.x * 4 + wv;            // 0..2499

    // B-frags + biases: hoisted ONCE per wave.
    // tiles 0-1 = W1 (64 ch -> x2), 2-5 = W2 (128 ch -> x3)
    bf16x8 bfr[6]; float bv[6];
#pragma unroll
    for (int tt = 0; tt < 6; ++tt) {
        bfr[tt] = (bf16x8){0,0,0,0,0,0,0,0};
        const float* Wrow;
        if (tt < 2) { Wrow = W1 + (size_t)(tt*32 + c31) * 4;     bv[tt] = B1[tt*32 + c31]; }
        else        { Wrow = W2 + (size_t)((tt-2)*32 + c31) * 4; bv[tt] = B2[(tt-2)*32 + c31]; }
        if (hi == 0) {
            const float4 w4 = *(const float4*)Wrow;
            bfr[tt][0]=f2bs(w4.x); bfr[tt][1]=f2bs(w4.y);
            bfr[tt][2]=f2bs(w4.z); bfr[tt][3]=f2bs(w4.w);
        }
    }
    f32x16 ZR;
#pragma unroll
    for (int i = 0; i < 16; ++i) ZR[i] = 0.f;

    // prefetch pair 0's geom data
    float4 g = (float4){0.f,0.f,0.f,0.f};
    if (hi == 0)
        g = *(const float4*)(geom +
            ((size_t)((wglob * 8) * 2 + (c31 >> 4)) * KNN + (c31 & 15)) * 4);

#pragma unroll
    for (int it = 0; it < 8; ++it) {
        const int p0 = (wglob * 8 + it) * 2;
        const float4 gc = g;
        if (it < 7 && hi == 0)                        // prefetch next pair
            g = *(const float4*)(geom +
                ((size_t)(p0 + 2 + (c31 >> 4)) * KNN + (c31 & 15)) * 4);

        // A-frag: row = lane&31 -> (pt = row>>4, k = row&15); cols 0..3 real.
        bf16x8 a = (bf16x8){0,0,0,0,0,0,0,0};
        if (hi == 0) { a[0]=f2bs(gc.x); a[1]=f2bs(gc.y); a[2]=f2bs(gc.z); a[3]=f2bs(gc.w); }

        f32x16 acc[6];
#pragma unroll
        for (int tt = 0; tt < 6; ++tt)
            acc[tt] = __builtin_amdgcn_mfma_f32_32x32x16_bf16(a, bfr[tt], ZR, 0, 0, 0);

        // Epilogue: regs 0-7 -> pt A rows, 8-15 -> pt B rows; each lane covers
        // 8 of 16 rows of each point; shfl_xor(32) completes the mean.
#pragma unroll
        for (int tt = 0; tt < 6; ++tt) {
            float sA = 0.f, sB = 0.f;
#pragma unroll
            for (int i = 0; i < 8; ++i)  sA += lrelu(acc[tt][i]     + bv[tt]);
#pragma unroll
            for (int i = 0; i < 8; ++i)  sB += lrelu(acc[tt][i + 8] + bv[tt]);
            sA += __shfl_xor(sA, 32, 64);
            sB += __shfl_xor(sB, 32, 64);
            const float s = (hi ? sB : sA) * (1.f / 16.f);
            const short v = f2bs(s);
            if (tt < 2) ((short*)x2)[(size_t)(p0 + hi) * 128 + tt*32 + c31] = v;
            else        ((short*)x3)[(size_t)(p0 + hi) * 256 + (tt-2)*32 + c31] = v;
        }
    }
}

// ---------------------------------------------------------------------------
// gather-mean of x1 rows -> x2[:,64:128]. 8 lanes/point; each lane loads 2
// indices, neighbors broadcast via __shfl (no redundant idx loads).
// ---------------------------------------------------------------------------
__global__ void __launch_bounds__(256) gather1_kernel(
    const int* __restrict__ idxw, const int* __restrict__ flag,
    const __hip_bfloat16* __restrict__ x1,    // [BN,64]
    __hip_bfloat16* __restrict__ x2)          // [BN,128]
{
    int t = blockIdx.x * 256 + threadIdx.x;   // 320000 exactly = BN*8
    int p = t >> 3, j = t & 7;
    int lane = threadIdx.x & 63;
    int dual = (*flag == 0) ? 2 : 1;
    int base = (p >= NPTS) ? NPTS : 0;
    int i0 = idxw[((size_t)p * 16 + 2*j)     * dual];   // neighbor 2j
    int i1 = idxw[((size_t)p * 16 + 2*j + 1) * dual];   // neighbor 2j+1
    int g8 = lane & 56;
    float acc[8];
#pragma unroll
    for (int i = 0; i < 8; ++i) acc[i] = 0.f;
#pragma unroll
    for (int k = 0; k < 8; ++k) {
        int rA = base + __shfl(i0, g8 + k, 64);         // neighbor 2k
        int rB = base + __shfl(i1, g8 + k, 64);         // neighbor 2k+1
        bf16x8 vA = *(const bf16x8*)((const short*)x1 + (size_t)rA * 64 + j * 8);
        bf16x8 vB = *(const bf16x8*)((const short*)x1 + (size_t)rB * 64 + j * 8);
#pragma unroll
        for (int i = 0; i < 8; ++i) acc[i] += bs2f(vA[i]) + bs2f(vB[i]);
    }
    bf16x8 o;
#pragma unroll
    for (int i = 0; i < 8; ++i) o[i] = f2bs(acc[i] * (1.f/16.f));
    *(bf16x8*)((short*)x2 + (size_t)p * 128 + 64 + j * 8) = o;
}

// ---------------------------------------------------------------------------
// gather-mean of x2 rows -> x3[:,128:256]. 16 lanes/point; each lane loads 1
// index, neighbors broadcast via __shfl.
// ---------------------------------------------------------------------------
__global__ void __launch_bounds__(256) gather2_kernel(
    const int* __restrict__ idxw, const int* __restrict__ flag,
    const __hip_bfloat16* __restrict__ x2,    // [BN,128]
    __hip_bfloat16* __restrict__ x3)          // [BN,256]
{
    int t = blockIdx.x * 256 + threadIdx.x;   // 640000 exactly = BN*16
    int p = t >> 4, j = t & 15;
    int lane = threadIdx.x & 63;
    int dual = (*flag == 0) ? 2 : 1;
    int base = (p >= NPTS) ? NPTS : 0;
    int myi = idxw[((size_t)p * 16 + j) * dual];
    int g16 = lane & 48;
    float acc[8];
#pragma unroll
    for (int i = 0; i < 8; ++i) acc[i] = 0.f;
#pragma unroll
    for (int k = 0; k < KNN; ++k) {
        int row = base + __shfl(myi, g16 + k, 64);
        bf16x8 v = *(const bf16x8*)((const short*)x2 + (size_t)row * 128 + j * 8);
#pragma unroll
        for (int i = 0; i < 8; ++i) acc[i] += bs2f(v[i]);
    }
    bf16x8 o;
#pragma unroll
    for (int i = 0; i < 8; ++i) o[i] = f2bs(acc[i] * (1.f/16.f));
    *(bf16x8*)((short*)x3 + (size_t)p * 256 + 128 + j * 8) = o;
}

// ---------------------------------------------------------------------------
// out = LR(x3 @ Wf^T + bf) + LR(input @ Wi^T + bi), fp32 out. MFMA.
// R17 col-QUARTER weight-stationary:
//   grid = 500 = 125 row-chunks x 4 col-quarters; block = 256 thr (4 waves,
//   each = one 16-row group). LDS 64 KB = 64 cols x K256 x BOTH mats,
//   remapped from Wt as 64 x 1 KB chunks [(mat*8+kk)*4+qq][n_local<64][8],
//   DMA'd ONCE (16 dma16/wave), ONE barrier. 2 blocks/CU -> two overlapping
//   DMA/compute streams per CU. Main loop: 5 tiles x 64 rows; A-frags
//   (x3 bf16 direct, RES raw float4 + lazy per-kk cvt) in regs; pure
//   ds_read+MFMA; no in-loop barriers, no W re-fetch.
//   B-read byte addr = r*16 + q*1024 + const -> quarter-wave conflict-free.
// ---------------------------------------------------------------------------
__global__ void __launch_bounds__(256, 2) final_mfma(
    const __hip_bfloat16* __restrict__ X3,    // [BN,256] bf16 ws
    const float* __restrict__ RES,            // [BN,256] fp32
    const short* __restrict__ Wt,             // tiled bf16 [kk][mat][q][n][8]
    const float* __restrict__ Bf,             // [256]
    const float* __restrict__ Bi,             // [256]
    float* __restrict__ OUT)                  // [BN,256] fp32
{
    __shared__ short lw[32768];               // 64 KB: col-quarter, both mats
    const int t    = threadIdx.x;
    const int wave = t >> 6, lane = t & 63;
    const int r = lane & 15, q = lane >> 4;
    const int cq = blockIdx.x & 3;            // col-quarter
    const int p0 = (blockIdx.x >> 2) * 320;   // 125 chunks x 320 rows = 40000

    // ---- prologue: DMA W col-quarter into LDS, once. 64 chunks x 1 KB.
    // chunk c = (mat*8+kk)*4+qq ; src slab s = (kk*2+mat)*4+qq (4 KB each).
    {
        const char* WtB = (const char*)Wt;
        char* L = (char*)lw;
#pragma unroll
        for (int i = 0; i < 16; ++i) {
            int c = wave * 16 + i;                 // 0..63
            int mat = c >> 5, kk = (c >> 2) & 7, qq = c & 3;
            int s = ((kk * 2 + mat) * 4 + qq);
            dma16(WtB + (size_t)s * 4096 + cq * 1024 + lane * 16,
                  L + c * 1024 + lane * 16);
        }
    }
    // bias regs for this wave's 64 cols
    const int cb = cq * 64;
    float bfv[4], biv[4];
#pragma unroll
    for (int nt = 0; nt < 4; ++nt) {
        bfv[nt] = Bf[cb + nt * 16 + r];
        biv[nt] = Bi[cb + nt * 16 + r];
    }
    __syncthreads();                          // the ONLY barrier

    // short-indexed: chunk c = c*512 shorts; mat f: c = kk*4+q; mat i: +32
    const short* bpf = lw + q * 512 + r * 8;                 // + kk*2048 + nt*128
    const short* bpi = bpf + 16384;                          // mat i (Wi)

#pragma unroll
    for (int tt = 0; tt < 5; ++tt) {
        const int row = p0 + tt * 64 + wave * 16 + r;
        const short* x3r = (const short*)X3 + (size_t)row * DIM + q * 8;
        const float* rsr = RES + (size_t)row * DIM + q * 8;

        // burst-issue all A loads for this tile (24 loads), cvt deferred
        bf16x8 a1[8];
        float4 rw[16];
#pragma unroll
        for (int kk = 0; kk < 8; ++kk) {
            rw[2*kk]   = ((const float4*)rsr)[kk * 8];
            rw[2*kk+1] = ((const float4*)rsr)[kk * 8 + 1];
            a1[kk] = *(const bf16x8*)(x3r + kk * 32);
        }

        f32x4 acc1[4], acc2[4];
#pragma unroll
        for (int nt = 0; nt < 4; ++nt) {
            acc1[nt] = (f32x4){0.f,0.f,0.f,0.f};
            acc2[nt] = (f32x4){0.f,0.f,0.f,0.f};
        }
#pragma unroll
        for (int kk = 0; kk < 8; ++kk) {
            bf16x8 a2;
            {
                const float4 lo = rw[2*kk], hi2 = rw[2*kk+1];
                a2[0]=f2bs(lo.x);  a2[1]=f2bs(lo.y);  a2[2]=f2bs(lo.z);  a2[3]=f2bs(lo.w);
                a2[4]=f2bs(hi2.x); a2[5]=f2bs(hi2.y); a2[6]=f2bs(hi2.z); a2[7]=f2bs(hi2.w);
            }
#pragma unroll
            for (int nt = 0; nt < 4; ++nt) {
                bf16x8 b1 = *(const bf16x8*)(bpf + kk * 2048 + nt * 128);
                bf16x8 b2 = *(const bf16x8*)(bpi + kk * 2048 + nt * 128);
                acc1[nt] = __builtin_amdgcn_mfma_f32_16x16x32_bf16(a1[kk], b1, acc1[nt], 0, 0, 0);
                acc2[nt] = __builtin_amdgcn_mfma_f32_16x16x32_bf16(a2,    b2, acc2[nt], 0, 0, 0);
            }
        }
        // epilogue: 16 rows x 64 cols per wave
#pragma unroll
        for (int nt = 0; nt < 4; ++nt) {
            const int col = cb + nt * 16 + r;
#pragma unroll
            for (int i = 0; i < 4; ++i) {
                float v = lrelu(acc1[nt][i] + bfv[nt]) + lrelu(acc2[nt][i] + biv[nt]);
                OUT[(size_t)(p0 + tt * 64 + wave * 16 + q * 4 + i) * DIM + col] = v;
            }
        }
    }
}

// ---------------------------------------------------------------------------
extern "C" void kernel_launch(void* const* d_in, const int* in_sizes, int n_in,
                              void* d_out, int out_size, void* d_ws, size_t ws_size,
                              hipStream_t stream)
{
    const float* input  = (const float*)d_in[0];   // [2,20000,256]
    const float* geom   = (const float*)d_in[1];   // [2,20000,16,4]
    const int*   idxw   = (const int*)d_in[2];     // int32/int64 (detected)
    const float* W_init = (const float*)d_in[3];   // [64,256]
    const float* b_init = (const float*)d_in[4];
    const float* W_l1   = (const float*)d_in[5];   // [64,4]
    const float* b_l1   = (const float*)d_in[6];
    const float* W_l2   = (const float*)d_in[7];   // [128,4]
    const float* b_l2   = (const float*)d_in[8];
    const float* W_fin  = (const float*)d_in[9];   // [256,256]
    const float* b_fin  = (const float*)d_in[10];
    const float* W_id   = (const float*)d_in[11];  // [256,256]
    const float* b_id   = (const float*)d_in[12];
    float* out = (float*)d_out;                    // [2,20000,256] fp32

    // ws layout (<= 35.84 MB, proven safe R4-R16):
    //   flag @0 (16B)
    //   Wt  tiled bf16 256KB @16 ; Wnt tiled bf16 32KB @16+262144
    //   x2  [BN,128] bf16 @16+5.12e6
    //   x3  [BN,256] bf16 @16+15.36e6
    // x1 [BN,64] bf16 lives in d_out scratch; consumed by gather1, then
    // final_mfma overwrites all of d_out.
    char* ws = (char*)d_ws;
    int* flag = (int*)ws;
    short* Wt  = (short*)(ws + 16);
    short* Wnt = (short*)(ws + 16 + 262144);
    __hip_bfloat16* x2 = (__hip_bfloat16*)(ws + 16 + 5120000);
    __hip_bfloat16* x3 = (__hip_bfloat16*)(ws + 16 + 15360000);
    __hip_bfloat16* x1 = (__hip_bfloat16*)d_out;   // scratch, dead after gather1

    prep_kernel<<<145, 256, 0, stream>>>(idxw, flag, W_fin, W_id, W_init,
                                         Wt, Wnt);
    stage2_kernel<<<1250, 256, 0, stream>>>(geom, W_l1, b_l1, W_l2, b_l2,
                                            input, Wnt, b_init, x2, x3, x1);
    gather1_kernel<<<1250, 256, 0, stream>>>(idxw, flag, x1, x2);
    gather2_kernel<<<2500, 256, 0, stream>>>(idxw, flag, x2, x3);
    final_mfma<<<500, 256, 0, stream>>>(x3, input, Wt, b_fin, b_id, out);
}

// Round 8
// 204.806 us; speedup vs baseline: 1.8546x; 1.0272x over previous
//
#include <hip/hip_runtime.h>
#include <hip/hip_bf16.h>

// Problem constants (reference: B=2, N=20000, K=16, DIM=256)
// Established facts (R1-R18):
//   - float tensors fp32; idx int32/int64 runtime-detected; d_out fp32
//   - MFMA 16x16x32_bf16 gemm-BT fragments + C/D map verified
//   - R5-R8: global->VGPR weight loads serialize; use LDS (DMA) for weights.
//   - R11: final weight-stationary col-HALF (250x512, 128 KB LDS, one
//     barrier, 5x64-row tiles) = 39.4 us. KNOWN GOOD (restored here).
//   - R12-R14: dispatches are latency/ramp-bound; co-dispatch of independent
//     work is the only fusion that won (-10.6 -> 195.8 BEST).
//   - R15 REGRESSION: gather2-in-final (dup gather per col-half, L2 thrash).
//   - R16 REGRESSION: mega cooperative kernel capped gather occupancy
//     (8 waves/CU) -> gathers 3-4x slower. Never cap gather occupancy.
//   - R17 REGRESSION: col-QUARTER final: 4x A re-reads are NOT L3-absorbed
//     (FETCH 31->127 MB, 49.5 us). Col-half is the sweet spot. Reverted.
//   - R18 (this round): (a) final reverted to R11 col-half. (b) prep dispatch
//     DELETED: mlp blocks self-convert W_init->LDS (L3-hot); Wt-conv+detect
//     are block-range 1250..1378 of stage2 (outputs consumed >=1 dispatch
//     later). Chain = 4 dispatches. (c) gathers take 2 points/thread
//     (p and p+NPTS: same j, shfl groups align since 160000%64==0) ->
//     2x outstanding loads, half the latency rounds, half the blocks.
//   - LDS quarter-wave phasing: byte addr = r*16 + q*(multiple of 1 KB) +
//     const is conflict-free (R9/R11 measured 0).
#define BN   40000
#define NPTS 20000
#define KNN  16
#define DIM  256

typedef __attribute__((ext_vector_type(8))) short bf16x8;   // 8 bf16 = 4 VGPRs
typedef __attribute__((ext_vector_type(4))) float f32x4;
typedef __attribute__((ext_vector_type(16))) float f32x16;

__device__ __forceinline__ float lrelu(float v) { return fmaxf(v, 0.1f * v); }
__device__ __forceinline__ float bs2f(short s) {
    union { unsigned u; float f; } c; c.u = ((unsigned)(unsigned short)s) << 16;
    return c.f;
}
__device__ __forceinline__ short f2bs(float f) {
    __hip_bfloat16 h = __float2bfloat16(f);           // RNE
    return *reinterpret_cast<short*>(&h);
}
__device__ __forceinline__ bf16x8 ldf32_bf16x8(const float* p) {
    const float4 a = ((const float4*)p)[0];
    const float4 b = ((const float4*)p)[1];
    bf16x8 r;
    r[0]=f2bs(a.x); r[1]=f2bs(a.y); r[2]=f2bs(a.z); r[3]=f2bs(a.w);
    r[4]=f2bs(b.x); r[5]=f2bs(b.y); r[6]=f2bs(b.z); r[7]=f2bs(b.w);
    return r;
}

// async global->LDS, 16 B per lane; lds dst = wave-uniform base + lane*16.
__device__ __forceinline__ void dma16(const void* g, void* l) {
    __builtin_amdgcn_global_load_lds(
        (const __attribute__((address_space(1))) unsigned int*)g,
        (__attribute__((address_space(3))) unsigned int*)l, 16, 0, 0);
}

// ---------------------------------------------------------------------------
// stage2: geom MLPs (blocks 0..624) + mlp_init (625..1249) + Wt weight
// conversion (1250..1377) + idx-dtype detect (1378). All mutually
// independent inside this dispatch:
//   geom: reads geom,W1,W2 -> x2[:,0:64], x3[:,0:128]
//   mlp:  reads input, Wn (self-converted to LDS), b_init -> x1
//   conv: Wf,Wi -> tiled Wt (consumed by final, 3 dispatches later)
//   detect: -> flag (consumed by gather1, next dispatch)
// ---------------------------------------------------------------------------
__global__ void __launch_bounds__(256) stage2_kernel(
    const float* __restrict__ geom,      // [BN,16,4]
    const float* __restrict__ W1, const float* __restrict__ B1,   // [64,4],[64]
    const float* __restrict__ W2, const float* __restrict__ B2,   // [128,4],[128]
    const float* __restrict__ X,         // [BN,256] input
    const float* __restrict__ Wn,        // [64,256] W_init fp32
    const float* __restrict__ b_init,    // [64]
    const int* __restrict__ idxw,
    const float* __restrict__ Wf, const float* __restrict__ Wi,   // [256,256]
    short* __restrict__ Wt, int* __restrict__ flag,
    __hip_bfloat16* __restrict__ x2,     // [BN,128]
    __hip_bfloat16* __restrict__ x3,     // [BN,256]
    __hip_bfloat16* __restrict__ x1)     // [BN,64] bf16 (d_out scratch)
{
    __shared__ short wbuf[16384];        // 32 KB (mlp blocks only)

    if (blockIdx.x >= 1250) {
        if (blockIdx.x == 1378) {        // ---- detect block (no atomics) ----
            __shared__ int red[256];
            int t = threadIdx.x;
            int v = 0;
#pragma unroll
            for (int it = 0; it < 64; ++it)
                v |= idxw[2 * (t + it * 256) + 1];   // odd words, first 128 KB
            red[t] = v;
            __syncthreads();
            for (int s = 128; s > 0; s >>= 1) {
                if (t < s) red[t] |= red[t + s];
                __syncthreads();
            }
            if (t == 0) *flag = (red[0] != 0) ? 1 : 0;
            return;
        }
        // ---- Wt conversion blocks: Wf (t<16384) / Wi -> tiled Wt ----
        int t = (blockIdx.x - 1250) * 256 + threadIdx.x;   // < 32768 exactly
        int mat = (t >> 14) & 1;
        int tt  = t & 16383;
        float4 v = mat ? ((const float4*)Wi)[tt] : ((const float4*)Wf)[tt];
        int n  = tt >> 6;
        int k  = (tt & 63) * 4;
        int kk = k >> 5, q = (k >> 3) & 3, j = k & 7;
        short4 o; o.x=f2bs(v.x); o.y=f2bs(v.y); o.z=f2bs(v.z); o.w=f2bs(v.w);
        *(short4*)(Wt + ((size_t)((kk*2 + mat)*4 + q))*2048 + n*8 + j) = o;
        return;
    }

    if (blockIdx.x >= 625) {             // ---------------- mlp_init ----------
        int bid = blockIdx.x - 625;      // 0..624
        int t = threadIdx.x;
        int wave = t >> 6, lane = t & 63;
        int r = lane & 15, q = lane >> 4;
        // ---- self-convert W_init -> wbuf tiled [kk][q][64][8] (L3-hot) ----
        {
            const float4* Wn4 = (const float4*)Wn;
#pragma unroll
            for (int i = 0; i < 16; ++i) {
                int tt = t * 16 + i;              // 0..4095
                float4 v = Wn4[tt];
                int n  = tt >> 6;
                int k  = (tt & 63) * 4;
                int kk = k >> 5, qq = (k >> 3) & 3, j = k & 7;
                short4 o; o.x=f2bs(v.x); o.y=f2bs(v.y); o.z=f2bs(v.z); o.w=f2bs(v.w);
                *(short4*)&wbuf[((kk*4 + qq)*64 + n)*8 + j] = o;
            }
        }
        int m0 = bid * 64 + wave * 16;
        const float4* X4 = (const float4*)(X + (size_t)(m0 + r) * DIM + q * 8);
        bf16x8 a[8];
        // burst 8 raw float4 loads, then convert (2 groups of 4 kk)
#pragma unroll
        for (int g = 0; g < 2; ++g) {
            float4 rwm[8];
#pragma unroll
            for (int kk = 0; kk < 4; ++kk) {
                rwm[2*kk]   = X4[(g*4 + kk) * 8];
                rwm[2*kk+1] = X4[(g*4 + kk) * 8 + 1];
            }
#pragma unroll
            for (int kk = 0; kk < 4; ++kk) {
                const float4 lo = rwm[2*kk], hi2 = rwm[2*kk+1];
                bf16x8 av;
                av[0]=f2bs(lo.x);  av[1]=f2bs(lo.y);  av[2]=f2bs(lo.z);  av[3]=f2bs(lo.w);
                av[4]=f2bs(hi2.x); av[5]=f2bs(hi2.y); av[6]=f2bs(hi2.z); av[7]=f2bs(hi2.w);
                a[g*4 + kk] = av;
            }
        }
        __syncthreads();                 // wbuf conversion writes visible

        f32x4 acc[4];
#pragma unroll
        for (int nt = 0; nt < 4; ++nt) acc[nt] = (f32x4){0.f,0.f,0.f,0.f};
#pragma unroll
        for (int kk = 0; kk < 8; ++kk) {
#pragma unroll
            for (int nt = 0; nt < 4; ++nt) {
                bf16x8 b = *(const bf16x8*)&wbuf[((kk*4 + q)*64 + nt*16 + r) * 8];
                acc[nt] = __builtin_amdgcn_mfma_f32_16x16x32_bf16(a[kk], b, acc[nt], 0, 0, 0);
            }
        }
#pragma unroll
        for (int nt = 0; nt < 4; ++nt) {
            int col = nt * 16 + r;
            float bvx = b_init[col];
#pragma unroll
            for (int i = 0; i < 4; ++i) {
                float v = lrelu(acc[nt][i] + bvx);
                x1[(size_t)(m0 + q*4 + i) * 64 + col] = __float2bfloat16(v);
            }
        }
        return;
    }

    // ---------------- geom: 625 blocks x 4 waves x 8 pairs = 40000 pts -----
    const int lane = threadIdx.x & 63;
    const int wv   = threadIdx.x >> 6;
    const int c31  = lane & 31;
    const int hi   = lane >> 5;
    const int wglob = blockIdx.x * 4 + wv;            // 0..2499

    // B-frags + biases: hoisted ONCE per wave.
    // tiles 0-1 = W1 (64 ch -> x2), 2-5 = W2 (128 ch -> x3)
    bf16x8 bfr[6]; float bv[6];
#pragma unroll
    for (int tt = 0; tt < 6; ++tt) {
        bfr[tt] = (bf16x8){0,0,0,0,0,0,0,0};
        const float* Wrow;
        if (tt < 2) { Wrow = W1 + (size_t)(tt*32 + c31) * 4;     bv[tt] = B1[tt*32 + c31]; }
        else        { Wrow = W2 + (size_t)((tt-2)*32 + c31) * 4; bv[tt] = B2[(tt-2)*32 + c31]; }
        if (hi == 0) {
            const float4 w4 = *(const float4*)Wrow;
            bfr[tt][0]=f2bs(w4.x); bfr[tt][1]=f2bs(w4.y);
            bfr[tt][2]=f2bs(w4.z); bfr[tt][3]=f2bs(w4.w);
        }
    }
    f32x16 ZR;
#pragma unroll
    for (int i = 0; i < 16; ++i) ZR[i] = 0.f;

    // prefetch pair 0's geom data
    float4 g = (float4){0.f,0.f,0.f,0.f};
    if (hi == 0)
        g = *(const float4*)(geom +
            ((size_t)((wglob * 8) * 2 + (c31 >> 4)) * KNN + (c31 & 15)) * 4);

#pragma unroll
    for (int it = 0; it < 8; ++it) {
        const int p0 = (wglob * 8 + it) * 2;
        const float4 gc = g;
        if (it < 7 && hi == 0)                        // prefetch next pair
            g = *(const float4*)(geom +
                ((size_t)(p0 + 2 + (c31 >> 4)) * KNN + (c31 & 15)) * 4);

        // A-frag: row = lane&31 -> (pt = row>>4, k = row&15); cols 0..3 real.
        bf16x8 a = (bf16x8){0,0,0,0,0,0,0,0};
        if (hi == 0) { a[0]=f2bs(gc.x); a[1]=f2bs(gc.y); a[2]=f2bs(gc.z); a[3]=f2bs(gc.w); }

        f32x16 acc[6];
#pragma unroll
        for (int tt = 0; tt < 6; ++tt)
            acc[tt] = __builtin_amdgcn_mfma_f32_32x32x16_bf16(a, bfr[tt], ZR, 0, 0, 0);

        // Epilogue: regs 0-7 -> pt A rows, 8-15 -> pt B rows; each lane covers
        // 8 of 16 rows of each point; shfl_xor(32) completes the mean.
#pragma unroll
        for (int tt = 0; tt < 6; ++tt) {
            float sA = 0.f, sB = 0.f;
#pragma unroll
            for (int i = 0; i < 8; ++i)  sA += lrelu(acc[tt][i]     + bv[tt]);
#pragma unroll
            for (int i = 0; i < 8; ++i)  sB += lrelu(acc[tt][i + 8] + bv[tt]);
            sA += __shfl_xor(sA, 32, 64);
            sB += __shfl_xor(sB, 32, 64);
            const float s = (hi ? sB : sA) * (1.f / 16.f);
            const short v = f2bs(s);
            if (tt < 2) ((short*)x2)[(size_t)(p0 + hi) * 128 + tt*32 + c31] = v;
            else        ((short*)x3)[(size_t)(p0 + hi) * 256 + (tt-2)*32 + c31] = v;
        }
    }
}

// ---------------------------------------------------------------------------
// gather-mean of x1 rows -> x2[:,64:128]. R18: 2 points/thread (p, p+NPTS):
// same j and same shfl-group alignment (160000 % 64 == 0); 4 idx loads +
// 32 gather loads outstanding per thread. Grid 625.
// ---------------------------------------------------------------------------
__global__ void __launch_bounds__(256) gather1_kernel(
    const int* __restrict__ idxw, const int* __restrict__ flag,
    const __hip_bfloat16* __restrict__ x1,    // [BN,64]
    __hip_bfloat16* __restrict__ x2)          // [BN,128]
{
    int t = blockIdx.x * 256 + threadIdx.x;   // 160000 exactly = NPTS*8
    int p = t >> 3, j = t & 7;                // p in [0, NPTS)
    int lane = threadIdx.x & 63;
    int dual = (*flag == 0) ? 2 : 1;
    int g8 = lane & 56;
    int iA0 = idxw[((size_t)p * 16 + 2*j)     * dual];
    int iA1 = idxw[((size_t)p * 16 + 2*j + 1) * dual];
    int iB0 = idxw[((size_t)(p + NPTS) * 16 + 2*j)     * dual];
    int iB1 = idxw[((size_t)(p + NPTS) * 16 + 2*j + 1) * dual];
    float aA[8], aB[8];
#pragma unroll
    for (int i = 0; i < 8; ++i) { aA[i] = 0.f; aB[i] = 0.f; }
#pragma unroll
    for (int k = 0; k < 8; ++k) {
        int rA0 = __shfl(iA0, g8 + k, 64);
        int rA1 = __shfl(iA1, g8 + k, 64);
        int rB0 = NPTS + __shfl(iB0, g8 + k, 64);
        int rB1 = NPTS + __shfl(iB1, g8 + k, 64);
        bf16x8 vA0 = *(const bf16x8*)((const short*)x1 + (size_t)rA0 * 64 + j * 8);
        bf16x8 vA1 = *(const bf16x8*)((const short*)x1 + (size_t)rA1 * 64 + j * 8);
        bf16x8 vB0 = *(const bf16x8*)((const short*)x1 + (size_t)rB0 * 64 + j * 8);
        bf16x8 vB1 = *(const bf16x8*)((const short*)x1 + (size_t)rB1 * 64 + j * 8);
#pragma unroll
        for (int i = 0; i < 8; ++i) {
            aA[i] += bs2f(vA0[i]) + bs2f(vA1[i]);
            aB[i] += bs2f(vB0[i]) + bs2f(vB1[i]);
        }
    }
    bf16x8 oA, oB;
#pragma unroll
    for (int i = 0; i < 8; ++i) {
        oA[i] = f2bs(aA[i] * (1.f/16.f));
        oB[i] = f2bs(aB[i] * (1.f/16.f));
    }
    *(bf16x8*)((short*)x2 + (size_t)p * 128 + 64 + j * 8) = oA;
    *(bf16x8*)((short*)x2 + (size_t)(p + NPTS) * 128 + 64 + j * 8) = oB;
}

// ---------------------------------------------------------------------------
// gather-mean of x2 rows -> x3[:,128:256]. R18: 2 points/thread (p, p+NPTS);
// 2 idx loads + 32 gather loads outstanding. Grid 1250.
// ---------------------------------------------------------------------------
__global__ void __launch_bounds__(256) gather2_kernel(
    const int* __restrict__ idxw, const int* __restrict__ flag,
    const __hip_bfloat16* __restrict__ x2,    // [BN,128]
    __hip_bfloat16* __restrict__ x3)          // [BN,256]
{
    int t = blockIdx.x * 256 + threadIdx.x;   // 320000 exactly = NPTS*16
    int p = t >> 4, j = t & 15;               // p in [0, NPTS)
    int lane = threadIdx.x & 63;
    int dual = (*flag == 0) ? 2 : 1;
    int g16 = lane & 48;
    int iA = idxw[((size_t)p * 16 + j) * dual];
    int iB = idxw[((size_t)(p + NPTS) * 16 + j) * dual];
    float aA[8], aB[8];
#pragma unroll
    for (int i = 0; i < 8; ++i) { aA[i] = 0.f; aB[i] = 0.f; }
#pragma unroll
    for (int k = 0; k < KNN; ++k) {
        int rA = __shfl(iA, g16 + k, 64);
        int rB = NPTS + __shfl(iB, g16 + k, 64);
        bf16x8 vA = *(const bf16x8*)((const short*)x2 + (size_t)rA * 128 + j * 8);
        bf16x8 vB = *(const bf16x8*)((const short*)x2 + (size_t)rB * 128 + j * 8);
#pragma unroll
        for (int i = 0; i < 8; ++i) {
            aA[i] += bs2f(vA[i]);
            aB[i] += bs2f(vB[i]);
        }
    }
    bf16x8 oA, oB;
#pragma unroll
    for (int i = 0; i < 8; ++i) {
        oA[i] = f2bs(aA[i] * (1.f/16.f));
        oB[i] = f2bs(aB[i] * (1.f/16.f));
    }
    *(bf16x8*)((short*)x3 + (size_t)p * 256 + 128 + j * 8) = oA;
    *(bf16x8*)((short*)x3 + (size_t)(p + NPTS) * 256 + 128 + j * 8) = oB;
}

// ---------------------------------------------------------------------------
// out = LR(x3 @ Wf^T + bf) + LR(input @ Wi^T + bi), fp32 out. MFMA.
// R11 weight-stationary col-HALF (KNOWN GOOD, 39.4 us; restored):
//   grid = 250 = 2 col-halves x 125 row-chunks (320 rows each).
//   block = 512 thr (8 waves = 4 row-groups x 2 col-groups of 64 cols).
//   LDS 128 KB = col-half of BOTH mats, remapped from Wt as 64 x 2 KB chunks
//   [(mat*8+kk)*4+q][n_local<128][8], DMA'd ONCE (16 dma16/wave), ONE barrier.
//   Main loop: 5 tiles x 64 rows; A-frags (X3 bf16 direct, RES raw float4 +
//   lazy per-kk cvt) in regs; pure ds_read+MFMA; NO barriers, no W re-fetch.
//   B-read byte addr = const + q*2048 + r*16 -> quarter-wave conflict-free.
// ---------------------------------------------------------------------------
__global__ void __launch_bounds__(512, 2) final_mfma(
    const __hip_bfloat16* __restrict__ X3,    // [BN,256] bf16 ws
    const float* __restrict__ RES,            // [BN,256] fp32
    const short* __restrict__ Wt,             // tiled bf16 [kk][mat][q][n][8]
    const float* __restrict__ Bf,             // [256]
    const float* __restrict__ Bi,             // [256]
    float* __restrict__ OUT)                  // [BN,256] fp32
{
    __shared__ short lw[65536];               // 128 KB: col-half, both mats
    const int t    = threadIdx.x;
    const int wave = t >> 6, lane = t & 63;
    const int r = lane & 15, q = lane >> 4;
    const int rg = wave >> 1, cg = wave & 1;  // 4 row-groups x 2 col-groups
    const int ch = blockIdx.x & 1;            // col-half
    const int p0 = (blockIdx.x >> 1) * 320;   // 125 chunks x 320 rows = 40000

    // ---- prologue: DMA W col-half into LDS, once. 64 chunks x 2 KB.
    // chunk c = (mat*8+kk)*4+qq ; src = Wt[(kk*2+mat)*4+qq] + ch*128 cols.
    {
        const char* WtB = (const char*)Wt;
        char* L = (char*)lw;
#pragma unroll
        for (int i = 0; i < 16; ++i) {
            int c = wave * 8 + (i >> 1);           // 0..63
            int d = i & 1;                          // half-chunk (1 KB)
            int mat = c >> 5, kk = (c >> 2) & 7, qq = c & 3;
            int src_sh = ((kk * 2 + mat) * 4 + qq) * 2048 + ch * 1024;
            dma16(WtB + (size_t)src_sh * 2 + d * 1024 + lane * 16,
                  L + (c * 2 + d) * 1024 + lane * 16);
        }
    }
    // bias regs for this wave's 64 cols
    const int cb = ch * 128 + cg * 64;
    float bfv[4], biv[4];
#pragma unroll
    for (int nt = 0; nt < 4; ++nt) {
        bfv[nt] = Bf[cb + nt * 16 + r];
        biv[nt] = Bi[cb + nt * 16 + r];
    }
    __syncthreads();                          // the ONLY barrier

    const short* bpf = lw + q * 1024 + (cg * 64 + r) * 8;   // mat f (Wf)
    const short* bpi = bpf + 32768;                          // mat i (Wi)

#pragma unroll
    for (int tt = 0; tt < 5; ++tt) {
        const int row = p0 + tt * 64 + rg * 16 + r;
        const short* x3r = (const short*)X3 + (size_t)row * DIM + q * 8;
        const float* rsr = RES + (size_t)row * DIM + q * 8;

        // burst-issue all A loads for this tile (24 loads), cvt deferred
        bf16x8 a1[8];
        float4 rw[16];
#pragma unroll
        for (int kk = 0; kk < 8; ++kk) {
            rw[2*kk]   = ((const float4*)rsr)[kk * 8];
            rw[2*kk+1] = ((const float4*)rsr)[kk * 8 + 1];
            a1[kk] = *(const bf16x8*)(x3r + kk * 32);
        }

        f32x4 acc1[4], acc2[4];
#pragma unroll
        for (int nt = 0; nt < 4; ++nt) {
            acc1[nt] = (f32x4){0.f,0.f,0.f,0.f};
            acc2[nt] = (f32x4){0.f,0.f,0.f,0.f};
        }
#pragma unroll
        for (int kk = 0; kk < 8; ++kk) {
            bf16x8 a2;
            {
                const float4 lo = rw[2*kk], hi2 = rw[2*kk+1];
                a2[0]=f2bs(lo.x);  a2[1]=f2bs(lo.y);  a2[2]=f2bs(lo.z);  a2[3]=f2bs(lo.w);
                a2[4]=f2bs(hi2.x); a2[5]=f2bs(hi2.y); a2[6]=f2bs(hi2.z); a2[7]=f2bs(hi2.w);
            }
#pragma unroll
            for (int nt = 0; nt < 4; ++nt) {
                bf16x8 b1 = *(const bf16x8*)(bpf + kk * 4096 + nt * 128);
                bf16x8 b2 = *(const bf16x8*)(bpi + kk * 4096 + nt * 128);
                acc1[nt] = __builtin_amdgcn_mfma_f32_16x16x32_bf16(a1[kk], b1, acc1[nt], 0, 0, 0);
                acc2[nt] = __builtin_amdgcn_mfma_f32_16x16x32_bf16(a2,    b2, acc2[nt], 0, 0, 0);
            }
        }
        // epilogue: 16 rows x 64 cols per wave
#pragma unroll
        for (int nt = 0; nt < 4; ++nt) {
            const int col = cb + nt * 16 + r;
#pragma unroll
            for (int i = 0; i < 4; ++i) {
                float v = lrelu(acc1[nt][i] + bfv[nt]) + lrelu(acc2[nt][i] + biv[nt]);
                OUT[(size_t)(p0 + tt * 64 + rg * 16 + q * 4 + i) * DIM + col] = v;
            }
        }
    }
}

// ---------------------------------------------------------------------------
extern "C" void kernel_launch(void* const* d_in, const int* in_sizes, int n_in,
                              void* d_out, int out_size, void* d_ws, size_t ws_size,
                              hipStream_t stream)
{
    const float* input  = (const float*)d_in[0];   // [2,20000,256]
    const float* geom   = (const float*)d_in[1];   // [2,20000,16,4]
    const int*   idxw   = (const int*)d_in[2];     // int32/int64 (detected)
    const float* W_init = (const float*)d_in[3];   // [64,256]
    const float* b_init = (const float*)d_in[4];
    const float* W_l1   = (const float*)d_in[5];   // [64,4]
    const float* b_l1   = (const float*)d_in[6];
    const float* W_l2   = (const float*)d_in[7];   // [128,4]
    const float* b_l2   = (const float*)d_in[8];
    const float* W_fin  = (const float*)d_in[9];   // [256,256]
    const float* b_fin  = (const float*)d_in[10];
    const float* W_id   = (const float*)d_in[11];  // [256,256]
    const float* b_id   = (const float*)d_in[12];
    float* out = (float*)d_out;                    // [2,20000,256] fp32

    // ws layout (<= 35.84 MB, proven safe R4-R17):
    //   flag @0 (16B)
    //   Wt  tiled bf16 256KB @16
    //   x2  [BN,128] bf16 @16+5.12e6
    //   x3  [BN,256] bf16 @16+15.36e6
    // x1 [BN,64] bf16 lives in d_out scratch; consumed by gather1, then
    // final_mfma overwrites all of d_out.
    char* ws = (char*)d_ws;
    int* flag = (int*)ws;
    short* Wt  = (short*)(ws + 16);
    __hip_bfloat16* x2 = (__hip_bfloat16*)(ws + 16 + 5120000);
    __hip_bfloat16* x3 = (__hip_bfloat16*)(ws + 16 + 15360000);
    __hip_bfloat16* x1 = (__hip_bfloat16*)d_out;   // scratch, dead after gather1

    stage2_kernel<<<1379, 256, 0, stream>>>(geom, W_l1, b_l1, W_l2, b_l2,
                                            input, W_init, b_init,
                                            idxw, W_fin, W_id, Wt, flag,
                                            x2, x3, x1);
    gather1_kernel<<<625, 256, 0, stream>>>(idxw, flag, x1, x2);
    gather2_kernel<<<1250, 256, 0, stream>>>(idxw, flag, x2, x3);
    final_mfma<<<250, 512, 0, stream>>>(x3, input, Wt, b_fin, b_id, out);
}

// Round 10
// 198.296 us; speedup vs baseline: 1.9154x; 1.0328x over previous
//
#include <hip/hip_runtime.h>
#include <hip/hip_bf16.h>

// Problem constants (reference: B=2, N=20000, K=16, DIM=256)
// Established facts (R1-R20):
//   - float tensors fp32; idx int32/int64 runtime-detected; d_out fp32
//   - MFMA 16x16x32_bf16 gemm-BT fragments + C/D map verified
//   - R5-R8: global->VGPR weight loads serialize; use LDS (DMA) for weights.
//   - R11: final weight-stationary col-HALF (250x512, 128 KB LDS) = 39.4 us.
//     KNOWN GOOD. R17 col-quarter REGRESSED (4x A re-reads NOT L3-absorbed).
//   - R12-R14: dispatches latency/ramp-bound; co-dispatch of independent
//     work wins (R14 = 195.8 BEST).
//   - R15 REGRESSION: gather2-in-final (dup work + L2 thrash).
//   - R16 REGRESSION: 128KB-LDS coop mega-kernel capped gather occupancy.
//   - R18 REGRESSIONS: 2-pt/thread gathers (-12 us: halved latency streams);
//     thread-major Wnt self-convert (480K LDS bank conflicts). Prep-fold
//     itself was +3 (kept).
//   - R19 FAILED correctness (absmax 0.369): coop gather12 merge (1250-block
//     cooperative launch + grid.sync between gather phases) — either silent
//     coop-launch failure under graph capture at >1 blk/CU or cross-phase
//     x2 visibility. DO NOT merge dependent gathers via grid.sync again
//     without a dedicated correctness probe. Dest-linear convert math was
//     verified independently (inverse of R18's harness-passed forward map).
//   - R20 (this round): recompose proven pieces only — stage2 w/ folded
//     conv+detect + DEST-LINEAR convert; gather1/gather2 as separate regular
//     dispatches with exact R14 bodies; R11 final. 4 dispatches.
//   - LDS quarter-wave phasing: byte addr = r*16 + q*(multiple of 1 KB) +
//     const is conflict-free (R9/R11 measured 0).
#define BN   40000
#define NPTS 20000
#define KNN  16
#define DIM  256

typedef __attribute__((ext_vector_type(8))) short bf16x8;   // 8 bf16 = 4 VGPRs
typedef __attribute__((ext_vector_type(4))) float f32x4;
typedef __attribute__((ext_vector_type(16))) float f32x16;

__device__ __forceinline__ float lrelu(float v) { return fmaxf(v, 0.1f * v); }
__device__ __forceinline__ float bs2f(short s) {
    union { unsigned u; float f; } c; c.u = ((unsigned)(unsigned short)s) << 16;
    return c.f;
}
__device__ __forceinline__ short f2bs(float f) {
    __hip_bfloat16 h = __float2bfloat16(f);           // RNE
    return *reinterpret_cast<short*>(&h);
}

// async global->LDS, 16 B per lane; lds dst = wave-uniform base + lane*16.
__device__ __forceinline__ void dma16(const void* g, void* l) {
    __builtin_amdgcn_global_load_lds(
        (const __attribute__((address_space(1))) unsigned int*)g,
        (__attribute__((address_space(3))) unsigned int*)l, 16, 0, 0);
}

// ---------------------------------------------------------------------------
// stage2: geom MLPs (blocks 0..624) + mlp_init (625..1249) + Wt weight
// conversion (1250..1377) + idx-dtype detect (1378). All mutually
// independent inside this dispatch:
//   geom: reads geom,W1,W2 -> x2[:,0:64], x3[:,0:128]
//   mlp:  reads input, Wn (self-converted to LDS, dest-linear), b_init -> x1
//   conv: Wf,Wi -> tiled Wt (consumed by final, 3 dispatches later)
//   detect: -> flag (consumed by gather1, next dispatch)
// ---------------------------------------------------------------------------
__global__ void __launch_bounds__(256) stage2_kernel(
    const float* __restrict__ geom,      // [BN,16,4]
    const float* __restrict__ W1, const float* __restrict__ B1,   // [64,4],[64]
    const float* __restrict__ W2, const float* __restrict__ B2,   // [128,4],[128]
    const float* __restrict__ X,         // [BN,256] input
    const float* __restrict__ Wn,        // [64,256] W_init fp32
    const float* __restrict__ b_init,    // [64]
    const int* __restrict__ idxw,
    const float* __restrict__ Wf, const float* __restrict__ Wi,   // [256,256]
    short* __restrict__ Wt, int* __restrict__ flag,
    __hip_bfloat16* __restrict__ x2,     // [BN,128]
    __hip_bfloat16* __restrict__ x3,     // [BN,256]
    __hip_bfloat16* __restrict__ x1)     // [BN,64] bf16 (d_out scratch)
{
    __shared__ short wbuf[16384];        // 32 KB (mlp blocks only)

    if (blockIdx.x >= 1250) {
        if (blockIdx.x == 1378) {        // ---- detect block (no atomics) ----
            __shared__ int red[256];
            int t = threadIdx.x;
            int v = 0;
#pragma unroll
            for (int it = 0; it < 64; ++it)
                v |= idxw[2 * (t + it * 256) + 1];   // odd words, first 128 KB
            red[t] = v;
            __syncthreads();
            for (int s = 128; s > 0; s >>= 1) {
                if (t < s) red[t] |= red[t + s];
                __syncthreads();
            }
            if (t == 0) *flag = (red[0] != 0) ? 1 : 0;
            return;
        }
        // ---- Wt conversion blocks: Wf (t<16384) / Wi -> tiled Wt ----
        int t = (blockIdx.x - 1250) * 256 + threadIdx.x;   // < 32768 exactly
        int mat = (t >> 14) & 1;
        int tt  = t & 16383;
        float4 v = mat ? ((const float4*)Wi)[tt] : ((const float4*)Wf)[tt];
        int n  = tt >> 6;
        int k  = (tt & 63) * 4;
        int kk = k >> 5, q = (k >> 3) & 3, j = k & 7;
        short4 o; o.x=f2bs(v.x); o.y=f2bs(v.y); o.z=f2bs(v.z); o.w=f2bs(v.w);
        *(short4*)(Wt + ((size_t)((kk*2 + mat)*4 + q))*2048 + n*8 + j) = o;
        return;
    }

    if (blockIdx.x >= 625) {             // ---------------- mlp_init ----------
        int bid = blockIdx.x - 625;      // 0..624
        int t = threadIdx.x;
        int wave = t >> 6, lane = t & 63;
        int r = lane & 15, q = lane >> 4;
        // ---- self-convert W_init -> wbuf, DEST-LINEAR (conflict-free).
        // Forward (R18, harness-passed): src tt -> slot o = kk*512+q*128+2n+jh.
        // Inverse here: jh=o&1, n=(o>>1)&63, qq=(o>>7)&3, kk=o>>9;
        // src float4 = n*64 + kk*8 + qq*2 + jh. Consecutive t -> consecutive
        // 8B in LDS -> 2 lanes/bank = free.
        {
            const float4* Wn4 = (const float4*)Wn;
#pragma unroll
            for (int i = 0; i < 16; ++i) {
                int o  = i * 256 + t;             // 0..4095
                int jh = o & 1;
                int n  = (o >> 1) & 63;
                int qq = (o >> 7) & 3;
                int kk = o >> 9;
                float4 v = Wn4[n * 64 + kk * 8 + qq * 2 + jh];
                short4 s4; s4.x=f2bs(v.x); s4.y=f2bs(v.y); s4.z=f2bs(v.z); s4.w=f2bs(v.w);
                *(short4*)&wbuf[o * 4] = s4;
            }
        }
        int m0 = bid * 64 + wave * 16;
        const float4* X4 = (const float4*)(X + (size_t)(m0 + r) * DIM + q * 8);
        bf16x8 a[8];
        // burst 8 raw float4 loads, then convert (2 groups of 4 kk)
#pragma unroll
        for (int g = 0; g < 2; ++g) {
            float4 rwm[8];
#pragma unroll
            for (int kk = 0; kk < 4; ++kk) {
                rwm[2*kk]   = X4[(g*4 + kk) * 8];
                rwm[2*kk+1] = X4[(g*4 + kk) * 8 + 1];
            }
#pragma unroll
            for (int kk = 0; kk < 4; ++kk) {
                const float4 lo = rwm[2*kk], hi2 = rwm[2*kk+1];
                bf16x8 av;
                av[0]=f2bs(lo.x);  av[1]=f2bs(lo.y);  av[2]=f2bs(lo.z);  av[3]=f2bs(lo.w);
                av[4]=f2bs(hi2.x); av[5]=f2bs(hi2.y); av[6]=f2bs(hi2.z); av[7]=f2bs(hi2.w);
                a[g*4 + kk] = av;
            }
        }
        __syncthreads();                 // wbuf conversion writes visible

        f32x4 acc[4];
#pragma unroll
        for (int nt = 0; nt < 4; ++nt) acc[nt] = (f32x4){0.f,0.f,0.f,0.f};
#pragma unroll
        for (int kk = 0; kk < 8; ++kk) {
#pragma unroll
            for (int nt = 0; nt < 4; ++nt) {
                bf16x8 b = *(const bf16x8*)&wbuf[((kk*4 + q)*64 + nt*16 + r) * 8];
                acc[nt] = __builtin_amdgcn_mfma_f32_16x16x32_bf16(a[kk], b, acc[nt], 0, 0, 0);
            }
        }
#pragma unroll
        for (int nt = 0; nt < 4; ++nt) {
            int col = nt * 16 + r;
            float bvx = b_init[col];
#pragma unroll
            for (int i = 0; i < 4; ++i) {
                float v = lrelu(acc[nt][i] + bvx);
                x1[(size_t)(m0 + q*4 + i) * 64 + col] = __float2bfloat16(v);
            }
        }
        return;
    }

    // ---------------- geom: 625 blocks x 4 waves x 8 pairs = 40000 pts -----
    const int lane = threadIdx.x & 63;
    const int wv   = threadIdx.x >> 6;
    const int c31  = lane & 31;
    const int hi   = lane >> 5;
    const int wglob = blockIdx.x * 4 + wv;            // 0..2499

    // B-frags + biases: hoisted ONCE per wave.
    // tiles 0-1 = W1 (64 ch -> x2), 2-5 = W2 (128 ch -> x3)
    bf16x8 bfr[6]; float bv[6];
#pragma unroll
    for (int tt = 0; tt < 6; ++tt) {
        bfr[tt] = (bf16x8){0,0,0,0,0,0,0,0};
        const float* Wrow;
        if (tt < 2) { Wrow = W1 + (size_t)(tt*32 + c31) * 4;     bv[tt] = B1[tt*32 + c31]; }
        else        { Wrow = W2 + (size_t)((tt-2)*32 + c31) * 4; bv[tt] = B2[(tt-2)*32 + c31]; }
        if (hi == 0) {
            const float4 w4 = *(const float4*)Wrow;
            bfr[tt][0]=f2bs(w4.x); bfr[tt][1]=f2bs(w4.y);
            bfr[tt][2]=f2bs(w4.z); bfr[tt][3]=f2bs(w4.w);
        }
    }
    f32x16 ZR;
#pragma unroll
    for (int i = 0; i < 16; ++i) ZR[i] = 0.f;

    // prefetch pair 0's geom data
    float4 g = (float4){0.f,0.f,0.f,0.f};
    if (hi == 0)
        g = *(const float4*)(geom +
            ((size_t)((wglob * 8) * 2 + (c31 >> 4)) * KNN + (c31 & 15)) * 4);

#pragma unroll
    for (int it = 0; it < 8; ++it) {
        const int p0 = (wglob * 8 + it) * 2;
        const float4 gc = g;
        if (it < 7 && hi == 0)                        // prefetch next pair
            g = *(const float4*)(geom +
                ((size_t)(p0 + 2 + (c31 >> 4)) * KNN + (c31 & 15)) * 4);

        // A-frag: row = lane&31 -> (pt = row>>4, k = row&15); cols 0..3 real.
        bf16x8 a = (bf16x8){0,0,0,0,0,0,0,0};
        if (hi == 0) { a[0]=f2bs(gc.x); a[1]=f2bs(gc.y); a[2]=f2bs(gc.z); a[3]=f2bs(gc.w); }

        f32x16 acc[6];
#pragma unroll
        for (int tt = 0; tt < 6; ++tt)
            acc[tt] = __builtin_amdgcn_mfma_f32_32x32x16_bf16(a, bfr[tt], ZR, 0, 0, 0);

        // Epilogue: regs 0-7 -> pt A rows, 8-15 -> pt B rows; each lane covers
        // 8 of 16 rows of each point; shfl_xor(32) completes the mean.
#pragma unroll
        for (int tt = 0; tt < 6; ++tt) {
            float sA = 0.f, sB = 0.f;
#pragma unroll
            for (int i = 0; i < 8; ++i)  sA += lrelu(acc[tt][i]     + bv[tt]);
#pragma unroll
            for (int i = 0; i < 8; ++i)  sB += lrelu(acc[tt][i + 8] + bv[tt]);
            sA += __shfl_xor(sA, 32, 64);
            sB += __shfl_xor(sB, 32, 64);
            const float s = (hi ? sB : sA) * (1.f / 16.f);
            const short v = f2bs(s);
            if (tt < 2) ((short*)x2)[(size_t)(p0 + hi) * 128 + tt*32 + c31] = v;
            else        ((short*)x3)[(size_t)(p0 + hi) * 256 + (tt-2)*32 + c31] = v;
        }
    }
}

// ---------------------------------------------------------------------------
// gather-mean of x1 rows -> x2[:,64:128]. R14 body (proven). 8 lanes/point;
// each lane loads 2 indices, neighbors broadcast via __shfl.
// ---------------------------------------------------------------------------
__global__ void __launch_bounds__(256) gather1_kernel(
    const int* __restrict__ idxw, const int* __restrict__ flag,
    const __hip_bfloat16* __restrict__ x1,    // [BN,64]
    __hip_bfloat16* __restrict__ x2)          // [BN,128]
{
    int t = blockIdx.x * 256 + threadIdx.x;   // 320000 exactly = BN*8
    int p = t >> 3, j = t & 7;
    int lane = threadIdx.x & 63;
    int dual = (*flag == 0) ? 2 : 1;
    int base = (p >= NPTS) ? NPTS : 0;
    int i0 = idxw[((size_t)p * 16 + 2*j)     * dual];   // neighbor 2j
    int i1 = idxw[((size_t)p * 16 + 2*j + 1) * dual];   // neighbor 2j+1
    int g8 = lane & 56;
    float acc[8];
#pragma unroll
    for (int i = 0; i < 8; ++i) acc[i] = 0.f;
#pragma unroll
    for (int k = 0; k < 8; ++k) {
        int rA = base + __shfl(i0, g8 + k, 64);         // neighbor 2k
        int rB = base + __shfl(i1, g8 + k, 64);         // neighbor 2k+1
        bf16x8 vA = *(const bf16x8*)((const short*)x1 + (size_t)rA * 64 + j * 8);
        bf16x8 vB = *(const bf16x8*)((const short*)x1 + (size_t)rB * 64 + j * 8);
#pragma unroll
        for (int i = 0; i < 8; ++i) acc[i] += bs2f(vA[i]) + bs2f(vB[i]);
    }
    bf16x8 o;
#pragma unroll
    for (int i = 0; i < 8; ++i) o[i] = f2bs(acc[i] * (1.f/16.f));
    *(bf16x8*)((short*)x2 + (size_t)p * 128 + 64 + j * 8) = o;
}

// ---------------------------------------------------------------------------
// gather-mean of x2 rows -> x3[:,128:256]. R14 body (proven). 16 lanes/point;
// each lane loads 1 index, neighbors broadcast via __shfl.
// ---------------------------------------------------------------------------
__global__ void __launch_bounds__(256) gather2_kernel(
    const int* __restrict__ idxw, const int* __restrict__ flag,
    const __hip_bfloat16* __restrict__ x2,    // [BN,128]
    __hip_bfloat16* __restrict__ x3)          // [BN,256]
{
    int t = blockIdx.x * 256 + threadIdx.x;   // 640000 exactly = BN*16
    int p = t >> 4, j = t & 15;
    int lane = threadIdx.x & 63;
    int dual = (*flag == 0) ? 2 : 1;
    int base = (p >= NPTS) ? NPTS : 0;
    int myi = idxw[((size_t)p * 16 + j) * dual];
    int g16 = lane & 48;
    float acc[8];
#pragma unroll
    for (int i = 0; i < 8; ++i) acc[i] = 0.f;
#pragma unroll
    for (int k = 0; k < KNN; ++k) {
        int row = base + __shfl(myi, g16 + k, 64);
        bf16x8 v = *(const bf16x8*)((const short*)x2 + (size_t)row * 128 + j * 8);
#pragma unroll
        for (int i = 0; i < 8; ++i) acc[i] += bs2f(v[i]);
    }
    bf16x8 o;
#pragma unroll
    for (int i = 0; i < 8; ++i) o[i] = f2bs(acc[i] * (1.f/16.f));
    *(bf16x8*)((short*)x3 + (size_t)p * 256 + 128 + j * 8) = o;
}

// ---------------------------------------------------------------------------
// out = LR(x3 @ Wf^T + bf) + LR(input @ Wi^T + bi), fp32 out. MFMA.
// R11 weight-stationary col-HALF (KNOWN GOOD, 39.4 us):
//   grid = 250 = 2 col-halves x 125 row-chunks (320 rows each).
//   block = 512 thr (8 waves = 4 row-groups x 2 col-groups of 64 cols).
//   LDS 128 KB = col-half of BOTH mats, remapped from Wt as 64 x 2 KB chunks
//   [(mat*8+kk)*4+q][n_local<128][8], DMA'd ONCE (16 dma16/wave), ONE barrier.
//   Main loop: 5 tiles x 64 rows; A-frags (X3 bf16 direct, RES raw float4 +
//   lazy per-kk cvt) in regs; pure ds_read+MFMA; NO barriers, no W re-fetch.
//   B-read byte addr = const + q*2048 + r*16 -> quarter-wave conflict-free.
// ---------------------------------------------------------------------------
__global__ void __launch_bounds__(512, 2) final_mfma(
    const __hip_bfloat16* __restrict__ X3,    // [BN,256] bf16 ws
    const float* __restrict__ RES,            // [BN,256] fp32
    const short* __restrict__ Wt,             // tiled bf16 [kk][mat][q][n][8]
    const float* __restrict__ Bf,             // [256]
    const float* __restrict__ Bi,             // [256]
    float* __restrict__ OUT)                  // [BN,256] fp32
{
    __shared__ short lw[65536];               // 128 KB: col-half, both mats
    const int t    = threadIdx.x;
    const int wave = t >> 6, lane = t & 63;
    const int r = lane & 15, q = lane >> 4;
    const int rg = wave >> 1, cg2 = wave & 1; // 4 row-groups x 2 col-groups
    const int ch = blockIdx.x & 1;            // col-half
    const int p0 = (blockIdx.x >> 1) * 320;   // 125 chunks x 320 rows = 40000

    // ---- prologue: DMA W col-half into LDS, once. 64 chunks x 2 KB.
    // chunk c = (mat*8+kk)*4+qq ; src = Wt[(kk*2+mat)*4+qq] + ch*128 cols.
    {
        const char* WtB = (const char*)Wt;
        char* L = (char*)lw;
#pragma unroll
        for (int i = 0; i < 16; ++i) {
            int c = wave * 8 + (i >> 1);           // 0..63
            int d = i & 1;                          // half-chunk (1 KB)
            int mat = c >> 5, kk = (c >> 2) & 7, qq = c & 3;
            int src_sh = ((kk * 2 + mat) * 4 + qq) * 2048 + ch * 1024;
            dma16(WtB + (size_t)src_sh * 2 + d * 1024 + lane * 16,
                  L + (c * 2 + d) * 1024 + lane * 16);
        }
    }
    // bias regs for this wave's 64 cols
    const int cb = ch * 128 + cg2 * 64;
    float bfv[4], biv[4];
#pragma unroll
    for (int nt = 0; nt < 4; ++nt) {
        bfv[nt] = Bf[cb + nt * 16 + r];
        biv[nt] = Bi[cb + nt * 16 + r];
    }
    __syncthreads();                          // the ONLY barrier

    const short* bpf = lw + q * 1024 + (cg2 * 64 + r) * 8;  // mat f (Wf)
    const short* bpi = bpf + 32768;                          // mat i (Wi)

#pragma unroll
    for (int tt = 0; tt < 5; ++tt) {
        const int row = p0 + tt * 64 + rg * 16 + r;
        const short* x3r = (const short*)X3 + (size_t)row * DIM + q * 8;
        const float* rsr = RES + (size_t)row * DIM + q * 8;

        // burst-issue all A loads for this tile (24 loads), cvt deferred
        bf16x8 a1[8];
        float4 rw[16];
#pragma unroll
        for (int kk = 0; kk < 8; ++kk) {
            rw[2*kk]   = ((const float4*)rsr)[kk * 8];
            rw[2*kk+1] = ((const float4*)rsr)[kk * 8 + 1];
            a1[kk] = *(const bf16x8*)(x3r + kk * 32);
        }

        f32x4 acc1[4], acc2[4];
#pragma unroll
        for (int nt = 0; nt < 4; ++nt) {
            acc1[nt] = (f32x4){0.f,0.f,0.f,0.f};
            acc2[nt] = (f32x4){0.f,0.f,0.f,0.f};
        }
#pragma unroll
        for (int kk = 0; kk < 8; ++kk) {
            bf16x8 a2;
            {
                const float4 lo = rw[2*kk], hi2 = rw[2*kk+1];
                a2[0]=f2bs(lo.x);  a2[1]=f2bs(lo.y);  a2[2]=f2bs(lo.z);  a2[3]=f2bs(lo.w);
                a2[4]=f2bs(hi2.x); a2[5]=f2bs(hi2.y); a2[6]=f2bs(hi2.z); a2[7]=f2bs(hi2.w);
            }
#pragma unroll
            for (int nt = 0; nt < 4; ++nt) {
                bf16x8 b1 = *(const bf16x8*)(bpf + kk * 4096 + nt * 128);
                bf16x8 b2 = *(const bf16x8*)(bpi + kk * 4096 + nt * 128);
                acc1[nt] = __builtin_amdgcn_mfma_f32_16x16x32_bf16(a1[kk], b1, acc1[nt], 0, 0, 0);
                acc2[nt] = __builtin_amdgcn_mfma_f32_16x16x32_bf16(a2,    b2, acc2[nt], 0, 0, 0);
            }
        }
        // epilogue: 16 rows x 64 cols per wave
#pragma unroll
        for (int nt = 0; nt < 4; ++nt) {
            const int col = cb + nt * 16 + r;
#pragma unroll
            for (int i = 0; i < 4; ++i) {
                float v = lrelu(acc1[nt][i] + bfv[nt]) + lrelu(acc2[nt][i] + biv[nt]);
                OUT[(size_t)(p0 + tt * 64 + rg * 16 + q * 4 + i) * DIM + col] = v;
            }
        }
    }
}

// ---------------------------------------------------------------------------
extern "C" void kernel_launch(void* const* d_in, const int* in_sizes, int n_in,
                              void* d_out, int out_size, void* d_ws, size_t ws_size,
                              hipStream_t stream)
{
    const float* input  = (const float*)d_in[0];   // [2,20000,256]
    const float* geom   = (const float*)d_in[1];   // [2,20000,16,4]
    const int*   idxw   = (const int*)d_in[2];     // int32/int64 (detected)
    const float* W_init = (const float*)d_in[3];   // [64,256]
    const float* b_init = (const float*)d_in[4];
    const float* W_l1   = (const float*)d_in[5];   // [64,4]
    const float* b_l1   = (const float*)d_in[6];
    const float* W_l2   = (const float*)d_in[7];   // [128,4]
    const float* b_l2   = (const float*)d_in[8];
    const float* W_fin  = (const float*)d_in[9];   // [256,256]
    const float* b_fin  = (const float*)d_in[10];
    const float* W_id   = (const float*)d_in[11];  // [256,256]
    const float* b_id   = (const float*)d_in[12];
    float* out = (float*)d_out;                    // [2,20000,256] fp32

    // ws layout (<= 35.84 MB, proven safe R4-R18):
    //   flag @0 (16B)
    //   Wt  tiled bf16 256KB @16
    //   x2  [BN,128] bf16 @16+5.12e6
    //   x3  [BN,256] bf16 @16+15.36e6
    // x1 [BN,64] bf16 lives in d_out scratch; consumed by gather1, then
    // final_mfma overwrites all of d_out.
    char* ws = (char*)d_ws;
    int* flag = (int*)ws;
    short* Wt  = (short*)(ws + 16);
    __hip_bfloat16* x2 = (__hip_bfloat16*)(ws + 16 + 5120000);
    __hip_bfloat16* x3 = (__hip_bfloat16*)(ws + 16 + 15360000);
    __hip_bfloat16* x1 = (__hip_bfloat16*)d_out;   // scratch, dead after gather1

    stage2_kernel<<<1379, 256, 0, stream>>>(geom, W_l1, b_l1, W_l2, b_l2,
                                            input, W_init, b_init,
                                            idxw, W_fin, W_id, Wt, flag,
                                            x2, x3, x1);
    gather1_kernel<<<1250, 256, 0, stream>>>(idxw, flag, x1, x2);
    gather2_kernel<<<2500, 256, 0, stream>>>(idxw, flag, x2, x3);
    final_mfma<<<250, 512, 0, stream>>>(x3, input, Wt, b_fin, b_id, out);
}

// Round 11
// 196.805 us; speedup vs baseline: 1.9300x; 1.0076x over previous
//
#include <hip/hip_runtime.h>
#include <hip/hip_bf16.h>

// Problem constants (reference: B=2, N=20000, K=16, DIM=256)
// Established facts (R1-R21):
//   - float tensors fp32; idx int32/int64 runtime-detected; d_out fp32
//   - MFMA 16x16x32_bf16 gemm-BT fragments + C/D map verified
//   - R5-R8: global->VGPR weight loads serialize; use LDS (DMA) for weights.
//   - R11: final weight-stationary col-HALF (250x512, 128 KB LDS) = 39.4 us.
//     KNOWN GOOD. R17 col-quarter REGRESSED (4x A re-reads NOT L3-absorbed).
//   - R12-R14: dispatches latency/ramp-bound; co-dispatch of independent
//     work wins (R14 = 195.8 BEST).
//   - R15 REGRESSION: gather2-in-final (dup work + L2 thrash).
//   - R16 REGRESSION: 128KB-LDS coop mega-kernel capped gather occupancy.
//   - R18: 2-pt/thread gathers REGRESSED (halved latency streams). Prep-fold
//     kept. Thread-major Wnt convert: stage2 = 43.0 us (480K LDS write
//     conflicts ~4-way = cheap).
//   - R19 FAILED correctness: coop gather12 merge (grid.sync between
//     dependent gather phases under graph capture). Banned without probe.
//   - R20: dest-linear convert REGRESSED stage2 43->89.7 us (per-iter all
//     lanes share n -> 8-B writes on ~4 banks = ~16-way conflict, worse than
//     thread-major; also loses base+imm-offset load burst). Conflict COUNTER
//     was 0 only because stalls moved to scattered reads/issue. Lesson: a
//     zero in one counter does not mean the pattern is faster — time it.
//   - R21 (this round): single-variable experiment — revert convert to R18's
//     exact thread-major form (43 us measured); all else byte-identical to
//     R20 (passed, gathers/final at floors). Discriminates convert-regression
//     vs dispatch-gap variance.
//   - LDS quarter-wave phasing: byte addr = r*16 + q*(multiple of 1 KB) +
//     const is conflict-free (R9/R11 measured 0).
#define BN   40000
#define NPTS 20000
#define KNN  16
#define DIM  256

typedef __attribute__((ext_vector_type(8))) short bf16x8;   // 8 bf16 = 4 VGPRs
typedef __attribute__((ext_vector_type(4))) float f32x4;
typedef __attribute__((ext_vector_type(16))) float f32x16;

__device__ __forceinline__ float lrelu(float v) { return fmaxf(v, 0.1f * v); }
__device__ __forceinline__ float bs2f(short s) {
    union { unsigned u; float f; } c; c.u = ((unsigned)(unsigned short)s) << 16;
    return c.f;
}
__device__ __forceinline__ short f2bs(float f) {
    __hip_bfloat16 h = __float2bfloat16(f);           // RNE
    return *reinterpret_cast<short*>(&h);
}

// async global->LDS, 16 B per lane; lds dst = wave-uniform base + lane*16.
__device__ __forceinline__ void dma16(const void* g, void* l) {
    __builtin_amdgcn_global_load_lds(
        (const __attribute__((address_space(1))) unsigned int*)g,
        (__attribute__((address_space(3))) unsigned int*)l, 16, 0, 0);
}

// ---------------------------------------------------------------------------
// stage2: geom MLPs (blocks 0..624) + mlp_init (625..1249) + Wt weight
// conversion (1250..1377) + idx-dtype detect (1378). All mutually
// independent inside this dispatch:
//   geom: reads geom,W1,W2 -> x2[:,0:64], x3[:,0:128]
//   mlp:  reads input, Wn (self-converted to LDS, thread-major), b_init -> x1
//   conv: Wf,Wi -> tiled Wt (consumed by final, 3 dispatches later)
//   detect: -> flag (consumed by gather1, next dispatch)
// ---------------------------------------------------------------------------
__global__ void __launch_bounds__(256) stage2_kernel(
    const float* __restrict__ geom,      // [BN,16,4]
    const float* __restrict__ W1, const float* __restrict__ B1,   // [64,4],[64]
    const float* __restrict__ W2, const float* __restrict__ B2,   // [128,4],[128]
    const float* __restrict__ X,         // [BN,256] input
    const float* __restrict__ Wn,        // [64,256] W_init fp32
    const float* __restrict__ b_init,    // [64]
    const int* __restrict__ idxw,
    const float* __restrict__ Wf, const float* __restrict__ Wi,   // [256,256]
    short* __restrict__ Wt, int* __restrict__ flag,
    __hip_bfloat16* __restrict__ x2,     // [BN,128]
    __hip_bfloat16* __restrict__ x3,     // [BN,256]
    __hip_bfloat16* __restrict__ x1)     // [BN,64] bf16 (d_out scratch)
{
    __shared__ short wbuf[16384];        // 32 KB (mlp blocks only)

    if (blockIdx.x >= 1250) {
        if (blockIdx.x == 1378) {        // ---- detect block (no atomics) ----
            __shared__ int red[256];
            int t = threadIdx.x;
            int v = 0;
#pragma unroll
            for (int it = 0; it < 64; ++it)
                v |= idxw[2 * (t + it * 256) + 1];   // odd words, first 128 KB
            red[t] = v;
            __syncthreads();
            for (int s = 128; s > 0; s >>= 1) {
                if (t < s) red[t] |= red[t + s];
                __syncthreads();
            }
            if (t == 0) *flag = (red[0] != 0) ? 1 : 0;
            return;
        }
        // ---- Wt conversion blocks: Wf (t<16384) / Wi -> tiled Wt ----
        int t = (blockIdx.x - 1250) * 256 + threadIdx.x;   // < 32768 exactly
        int mat = (t >> 14) & 1;
        int tt  = t & 16383;
        float4 v = mat ? ((const float4*)Wi)[tt] : ((const float4*)Wf)[tt];
        int n  = tt >> 6;
        int k  = (tt & 63) * 4;
        int kk = k >> 5, q = (k >> 3) & 3, j = k & 7;
        short4 o; o.x=f2bs(v.x); o.y=f2bs(v.y); o.z=f2bs(v.z); o.w=f2bs(v.w);
        *(short4*)(Wt + ((size_t)((kk*2 + mat)*4 + q))*2048 + n*8 + j) = o;
        return;
    }

    if (blockIdx.x >= 625) {             // ---------------- mlp_init ----------
        int bid = blockIdx.x - 625;      // 0..624
        int t = threadIdx.x;
        int wave = t >> 6, lane = t & 63;
        int r = lane & 15, q = lane >> 4;
        // ---- self-convert W_init -> wbuf, THREAD-MAJOR (R18 exact form,
        // harness-passed, stage2=43.0 us measured). Per-thread consecutive
        // reads -> base+imm-offset 16-load burst; writes ~4-way conflicted
        // (480K counted) which is empirically cheap. R20's "conflict-free"
        // dest-linear variant was 2x slower — do not resurrect it.
        {
            const float4* Wn4 = (const float4*)Wn;
#pragma unroll
            for (int i = 0; i < 16; ++i) {
                int tt = t * 16 + i;              // 0..4095
                float4 v = Wn4[tt];
                int n  = tt >> 6;
                int k  = (tt & 63) * 4;
                int kk = k >> 5, qq = (k >> 3) & 3, j = k & 7;
                short4 o; o.x=f2bs(v.x); o.y=f2bs(v.y); o.z=f2bs(v.z); o.w=f2bs(v.w);
                *(short4*)&wbuf[((kk*4 + qq)*64 + n)*8 + j] = o;
            }
        }
        int m0 = bid * 64 + wave * 16;
        const float4* X4 = (const float4*)(X + (size_t)(m0 + r) * DIM + q * 8);
        bf16x8 a[8];
        // burst 8 raw float4 loads, then convert (2 groups of 4 kk)
#pragma unroll
        for (int g = 0; g < 2; ++g) {
            float4 rwm[8];
#pragma unroll
            for (int kk = 0; kk < 4; ++kk) {
                rwm[2*kk]   = X4[(g*4 + kk) * 8];
                rwm[2*kk+1] = X4[(g*4 + kk) * 8 + 1];
            }
#pragma unroll
            for (int kk = 0; kk < 4; ++kk) {
                const float4 lo = rwm[2*kk], hi2 = rwm[2*kk+1];
                bf16x8 av;
                av[0]=f2bs(lo.x);  av[1]=f2bs(lo.y);  av[2]=f2bs(lo.z);  av[3]=f2bs(lo.w);
                av[4]=f2bs(hi2.x); av[5]=f2bs(hi2.y); av[6]=f2bs(hi2.z); av[7]=f2bs(hi2.w);
                a[g*4 + kk] = av;
            }
        }
        __syncthreads();                 // wbuf conversion writes visible

        f32x4 acc[4];
#pragma unroll
        for (int nt = 0; nt < 4; ++nt) acc[nt] = (f32x4){0.f,0.f,0.f,0.f};
#pragma unroll
        for (int kk = 0; kk < 8; ++kk) {
#pragma unroll
            for (int nt = 0; nt < 4; ++nt) {
                bf16x8 b = *(const bf16x8*)&wbuf[((kk*4 + q)*64 + nt*16 + r) * 8];
                acc[nt] = __builtin_amdgcn_mfma_f32_16x16x32_bf16(a[kk], b, acc[nt], 0, 0, 0);
            }
        }
#pragma unroll
        for (int nt = 0; nt < 4; ++nt) {
            int col = nt * 16 + r;
            float bvx = b_init[col];
#pragma unroll
            for (int i = 0; i < 4; ++i) {
                float v = lrelu(acc[nt][i] + bvx);
                x1[(size_t)(m0 + q*4 + i) * 64 + col] = __float2bfloat16(v);
            }
        }
        return;
    }

    // ---------------- geom: 625 blocks x 4 waves x 8 pairs = 40000 pts -----
    const int lane = threadIdx.x & 63;
    const int wv   = threadIdx.x >> 6;
    const int c31  = lane & 31;
    const int hi   = lane >> 5;
    const int wglob = blockIdx.x * 4 + wv;            // 0..2499

    // B-frags + biases: hoisted ONCE per wave.
    // tiles 0-1 = W1 (64 ch -> x2), 2-5 = W2 (128 ch -> x3)
    bf16x8 bfr[6]; float bv[6];
#pragma unroll
    for (int tt = 0; tt < 6; ++tt) {
        bfr[tt] = (bf16x8){0,0,0,0,0,0,0,0};
        const float* Wrow;
        if (tt < 2) { Wrow = W1 + (size_t)(tt*32 + c31) * 4;     bv[tt] = B1[tt*32 + c31]; }
        else        { Wrow = W2 + (size_t)((tt-2)*32 + c31) * 4; bv[tt] = B2[(tt-2)*32 + c31]; }
        if (hi == 0) {
            const float4 w4 = *(const float4*)Wrow;
            bfr[tt][0]=f2bs(w4.x); bfr[tt][1]=f2bs(w4.y);
            bfr[tt][2]=f2bs(w4.z); bfr[tt][3]=f2bs(w4.w);
        }
    }
    f32x16 ZR;
#pragma unroll
    for (int i = 0; i < 16; ++i) ZR[i] = 0.f;

    // prefetch pair 0's geom data
    float4 g = (float4){0.f,0.f,0.f,0.f};
    if (hi == 0)
        g = *(const float4*)(geom +
            ((size_t)((wglob * 8) * 2 + (c31 >> 4)) * KNN + (c31 & 15)) * 4);

#pragma unroll
    for (int it = 0; it < 8; ++it) {
        const int p0 = (wglob * 8 + it) * 2;
        const float4 gc = g;
        if (it < 7 && hi == 0)                        // prefetch next pair
            g = *(const float4*)(geom +
                ((size_t)(p0 + 2 + (c31 >> 4)) * KNN + (c31 & 15)) * 4);

        // A-frag: row = lane&31 -> (pt = row>>4, k = row&15); cols 0..3 real.
        bf16x8 a = (bf16x8){0,0,0,0,0,0,0,0};
        if (hi == 0) { a[0]=f2bs(gc.x); a[1]=f2bs(gc.y); a[2]=f2bs(gc.z); a[3]=f2bs(gc.w); }

        f32x16 acc[6];
#pragma unroll
        for (int tt = 0; tt < 6; ++tt)
            acc[tt] = __builtin_amdgcn_mfma_f32_32x32x16_bf16(a, bfr[tt], ZR, 0, 0, 0);

        // Epilogue: regs 0-7 -> pt A rows, 8-15 -> pt B rows; each lane covers
        // 8 of 16 rows of each point; shfl_xor(32) completes the mean.
#pragma unroll
        for (int tt = 0; tt < 6; ++tt) {
            float sA = 0.f, sB = 0.f;
#pragma unroll
            for (int i = 0; i < 8; ++i)  sA += lrelu(acc[tt][i]     + bv[tt]);
#pragma unroll
            for (int i = 0; i < 8; ++i)  sB += lrelu(acc[tt][i + 8] + bv[tt]);
            sA += __shfl_xor(sA, 32, 64);
            sB += __shfl_xor(sB, 32, 64);
            const float s = (hi ? sB : sA) * (1.f / 16.f);
            const short v = f2bs(s);
            if (tt < 2) ((short*)x2)[(size_t)(p0 + hi) * 128 + tt*32 + c31] = v;
            else        ((short*)x3)[(size_t)(p0 + hi) * 256 + (tt-2)*32 + c31] = v;
        }
    }
}

// ---------------------------------------------------------------------------
// gather-mean of x1 rows -> x2[:,64:128]. R14 body (proven). 8 lanes/point;
// each lane loads 2 indices, neighbors broadcast via __shfl.
// ---------------------------------------------------------------------------
__global__ void __launch_bounds__(256) gather1_kernel(
    const int* __restrict__ idxw, const int* __restrict__ flag,
    const __hip_bfloat16* __restrict__ x1,    // [BN,64]
    __hip_bfloat16* __restrict__ x2)          // [BN,128]
{
    int t = blockIdx.x * 256 + threadIdx.x;   // 320000 exactly = BN*8
    int p = t >> 3, j = t & 7;
    int lane = threadIdx.x & 63;
    int dual = (*flag == 0) ? 2 : 1;
    int base = (p >= NPTS) ? NPTS : 0;
    int i0 = idxw[((size_t)p * 16 + 2*j)     * dual];   // neighbor 2j
    int i1 = idxw[((size_t)p * 16 + 2*j + 1) * dual];   // neighbor 2j+1
    int g8 = lane & 56;
    float acc[8];
#pragma unroll
    for (int i = 0; i < 8; ++i) acc[i] = 0.f;
#pragma unroll
    for (int k = 0; k < 8; ++k) {
        int rA = base + __shfl(i0, g8 + k, 64);         // neighbor 2k
        int rB = base + __shfl(i1, g8 + k, 64);         // neighbor 2k+1
        bf16x8 vA = *(const bf16x8*)((const short*)x1 + (size_t)rA * 64 + j * 8);
        bf16x8 vB = *(const bf16x8*)((const short*)x1 + (size_t)rB * 64 + j * 8);
#pragma unroll
        for (int i = 0; i < 8; ++i) acc[i] += bs2f(vA[i]) + bs2f(vB[i]);
    }
    bf16x8 o;
#pragma unroll
    for (int i = 0; i < 8; ++i) o[i] = f2bs(acc[i] * (1.f/16.f));
    *(bf16x8*)((short*)x2 + (size_t)p * 128 + 64 + j * 8) = o;
}

// ---------------------------------------------------------------------------
// gather-mean of x2 rows -> x3[:,128:256]. R14 body (proven). 16 lanes/point;
// each lane loads 1 index, neighbors broadcast via __shfl.
// ---------------------------------------------------------------------------
__global__ void __launch_bounds__(256) gather2_kernel(
    const int* __restrict__ idxw, const int* __restrict__ flag,
    const __hip_bfloat16* __restrict__ x2,    // [BN,128]
    __hip_bfloat16* __restrict__ x3)          // [BN,256]
{
    int t = blockIdx.x * 256 + threadIdx.x;   // 640000 exactly = BN*16
    int p = t >> 4, j = t & 15;
    int lane = threadIdx.x & 63;
    int dual = (*flag == 0) ? 2 : 1;
    int base = (p >= NPTS) ? NPTS : 0;
    int myi = idxw[((size_t)p * 16 + j) * dual];
    int g16 = lane & 48;
    float acc[8];
#pragma unroll
    for (int i = 0; i < 8; ++i) acc[i] = 0.f;
#pragma unroll
    for (int k = 0; k < KNN; ++k) {
        int row = base + __shfl(myi, g16 + k, 64);
        bf16x8 v = *(const bf16x8*)((const short*)x2 + (size_t)row * 128 + j * 8);
#pragma unroll
        for (int i = 0; i < 8; ++i) acc[i] += bs2f(v[i]);
    }
    bf16x8 o;
#pragma unroll
    for (int i = 0; i < 8; ++i) o[i] = f2bs(acc[i] * (1.f/16.f));
    *(bf16x8*)((short*)x3 + (size_t)p * 256 + 128 + j * 8) = o;
}

// ---------------------------------------------------------------------------
// out = LR(x3 @ Wf^T + bf) + LR(input @ Wi^T + bi), fp32 out. MFMA.
// R11 weight-stationary col-HALF (KNOWN GOOD, 39.4 us):
//   grid = 250 = 2 col-halves x 125 row-chunks (320 rows each).
//   block = 512 thr (8 waves = 4 row-groups x 2 col-groups of 64 cols).
//   LDS 128 KB = col-half of BOTH mats, remapped from Wt as 64 x 2 KB chunks
//   [(mat*8+kk)*4+q][n_local<128][8], DMA'd ONCE (16 dma16/wave), ONE barrier.
//   Main loop: 5 tiles x 64 rows; A-frags (X3 bf16 direct, RES raw float4 +
//   lazy per-kk cvt) in regs; pure ds_read+MFMA; NO barriers, no W re-fetch.
//   B-read byte addr = const + q*2048 + r*16 -> quarter-wave conflict-free.
// ---------------------------------------------------------------------------
__global__ void __launch_bounds__(512, 2) final_mfma(
    const __hip_bfloat16* __restrict__ X3,    // [BN,256] bf16 ws
    const float* __restrict__ RES,            // [BN,256] fp32
    const short* __restrict__ Wt,             // tiled bf16 [kk][mat][q][n][8]
    const float* __restrict__ Bf,             // [256]
    const float* __restrict__ Bi,             // [256]
    float* __restrict__ OUT)                  // [BN,256] fp32
{
    __shared__ short lw[65536];               // 128 KB: col-half, both mats
    const int t    = threadIdx.x;
    const int wave = t >> 6, lane = t & 63;
    const int r = lane & 15, q = lane >> 4;
    const int rg = wave >> 1, cg2 = wave & 1; // 4 row-groups x 2 col-groups
    const int ch = blockIdx.x & 1;            // col-half
    const int p0 = (blockIdx.x >> 1) * 320;   // 125 chunks x 320 rows = 40000

    // ---- prologue: DMA W col-half into LDS, once. 64 chunks x 2 KB.
    // chunk c = (mat*8+kk)*4+qq ; src = Wt[(kk*2+mat)*4+qq] + ch*128 cols.
    {
        const char* WtB = (const char*)Wt;
        char* L = (char*)lw;
#pragma unroll
        for (int i = 0; i < 16; ++i) {
            int c = wave * 8 + (i >> 1);           // 0..63
            int d = i & 1;                          // half-chunk (1 KB)
            int mat = c >> 5, kk = (c >> 2) & 7, qq = c & 3;
            int src_sh = ((kk * 2 + mat) * 4 + qq) * 2048 + ch * 1024;
            dma16(WtB + (size_t)src_sh * 2 + d * 1024 + lane * 16,
                  L + (c * 2 + d) * 1024 + lane * 16);
        }
    }
    // bias regs for this wave's 64 cols
    const int cb = ch * 128 + cg2 * 64;
    float bfv[4], biv[4];
#pragma unroll
    for (int nt = 0; nt < 4; ++nt) {
        bfv[nt] = Bf[cb + nt * 16 + r];
        biv[nt] = Bi[cb + nt * 16 + r];
    }
    __syncthreads();                          // the ONLY barrier

    const short* bpf = lw + q * 1024 + (cg2 * 64 + r) * 8;  // mat f (Wf)
    const short* bpi = bpf + 32768;                          // mat i (Wi)

#pragma unroll
    for (int tt = 0; tt < 5; ++tt) {
        const int row = p0 + tt * 64 + rg * 16 + r;
        const short* x3r = (const short*)X3 + (size_t)row * DIM + q * 8;
        const float* rsr = RES + (size_t)row * DIM + q * 8;

        // burst-issue all A loads for this tile (24 loads), cvt deferred
        bf16x8 a1[8];
        float4 rw[16];
#pragma unroll
        for (int kk = 0; kk < 8; ++kk) {
            rw[2*kk]   = ((const float4*)rsr)[kk * 8];
            rw[2*kk+1] = ((const float4*)rsr)[kk * 8 + 1];
            a1[kk] = *(const bf16x8*)(x3r + kk * 32);
        }

        f32x4 acc1[4], acc2[4];
#pragma unroll
        for (int nt = 0; nt < 4; ++nt) {
            acc1[nt] = (f32x4){0.f,0.f,0.f,0.f};
            acc2[nt] = (f32x4){0.f,0.f,0.f,0.f};
        }
#pragma unroll
        for (int kk = 0; kk < 8; ++kk) {
            bf16x8 a2;
            {
                const float4 lo = rw[2*kk], hi2 = rw[2*kk+1];
                a2[0]=f2bs(lo.x);  a2[1]=f2bs(lo.y);  a2[2]=f2bs(lo.z);  a2[3]=f2bs(lo.w);
                a2[4]=f2bs(hi2.x); a2[5]=f2bs(hi2.y); a2[6]=f2bs(hi2.z); a2[7]=f2bs(hi2.w);
            }
#pragma unroll
            for (int nt = 0; nt < 4; ++nt) {
                bf16x8 b1 = *(const bf16x8*)(bpf + kk * 4096 + nt * 128);
                bf16x8 b2 = *(const bf16x8*)(bpi + kk * 4096 + nt * 128);
                acc1[nt] = __builtin_amdgcn_mfma_f32_16x16x32_bf16(a1[kk], b1, acc1[nt], 0, 0, 0);
                acc2[nt] = __builtin_amdgcn_mfma_f32_16x16x32_bf16(a2,    b2, acc2[nt], 0, 0, 0);
            }
        }
        // epilogue: 16 rows x 64 cols per wave
#pragma unroll
        for (int nt = 0; nt < 4; ++nt) {
            const int col = cb + nt * 16 + r;
#pragma unroll
            for (int i = 0; i < 4; ++i) {
                float v = lrelu(acc1[nt][i] + bfv[nt]) + lrelu(acc2[nt][i] + biv[nt]);
                OUT[(size_t)(p0 + tt * 64 + rg * 16 + q * 4 + i) * DIM + col] = v;
            }
        }
    }
}

// ---------------------------------------------------------------------------
extern "C" void kernel_launch(void* const* d_in, const int* in_sizes, int n_in,
                              void* d_out, int out_size, void* d_ws, size_t ws_size,
                              hipStream_t stream)
{
    const float* input  = (const float*)d_in[0];   // [2,20000,256]
    const float* geom   = (const float*)d_in[1];   // [2,20000,16,4]
    const int*   idxw   = (const int*)d_in[2];     // int32/int64 (detected)
    const float* W_init = (const float*)d_in[3];   // [64,256]
    const float* b_init = (const float*)d_in[4];
    const float* W_l1   = (const float*)d_in[5];   // [64,4]
    const float* b_l1   = (const float*)d_in[6];
    const float* W_l2   = (const float*)d_in[7];   // [128,4]
    const float* b_l2   = (const float*)d_in[8];
    const float* W_fin  = (const float*)d_in[9];   // [256,256]
    const float* b_fin  = (const float*)d_in[10];
    const float* W_id   = (const float*)d_in[11];  // [256,256]
    const float* b_id   = (const float*)d_in[12];
    float* out = (float*)d_out;                    // [2,20000,256] fp32

    // ws layout (<= 35.84 MB, proven safe R4-R20):
    //   flag @0 (16B)
    //   Wt  tiled bf16 256KB @16
    //   x2  [BN,128] bf16 @16+5.12e6
    //   x3  [BN,256] bf16 @16+15.36e6
    // x1 [BN,64] bf16 lives in d_out scratch; consumed by gather1, then
    // final_mfma overwrites all of d_out.
    char* ws = (char*)d_ws;
    int* flag = (int*)ws;
    short* Wt  = (short*)(ws + 16);
    __hip_bfloat16* x2 = (__hip_bfloat16*)(ws + 16 + 5120000);
    __hip_bfloat16* x3 = (__hip_bfloat16*)(ws + 16 + 15360000);
    __hip_bfloat16* x1 = (__hip_bfloat16*)d_out;   // scratch, dead after gather1

    stage2_kernel<<<1379, 256, 0, stream>>>(geom, W_l1, b_l1, W_l2, b_l2,
                                            input, W_init, b_init,
                                            idxw, W_fin, W_id, Wt, flag,
                                            x2, x3, x1);
    gather1_kernel<<<1250, 256, 0, stream>>>(idxw, flag, x1, x2);
    gather2_kernel<<<2500, 256, 0, stream>>>(idxw, flag, x2, x3);
    final_mfma<<<250, 512, 0, stream>>>(x3, input, Wt, b_fin, b_id, out);
}